// Round 8
// baseline (250.926 us; speedup 1.0000x reference)
//
#include <hip/hip_runtime.h>
#include <hip/hip_bf16.h>
#include <math.h>

#define N_NODES  50000
#define N_EDGES  800000
#define E_TOT    850000   // + self loops
#define N_GRAPHS 512
#define IN_CH    58
#define K1P      64       // padded K for layer-1 MFMA
#define C1       256      // HEADS1 * H = 4*64
#define H1       4
#define C2       128
#define NEG_SLOPE 0.2f
#define SLOT_CAP 64       // fixed bucket capacity; P(Poisson(17) > 63) < 1e-13
#define NBUILD   208      // ceil(850000 / (256*16)) -- 16 edges per thread
#define NATT     3125     // 50000 / 16 -- 4 waves x 4 nodes per block
#define NBUCK    196      // ceil(50000 / 256) dst-range buckets
#define BCAP     5120     // per-bucket capacity; mean 4352, sigma 66 -> +11.7 sigma

typedef __attribute__((ext_vector_type(8))) short short8;
typedef __attribute__((ext_vector_type(4))) float f32x4;

__device__ __forceinline__ float lo16(unsigned u) { return __uint_as_float(u << 16); }
__device__ __forceinline__ float hi16(unsigned u) { return __uint_as_float(u & 0xffff0000u); }
__device__ __forceinline__ float leaky(float e) { return e > 0.f ? e : NEG_SLOPE * e; }
__device__ __forceinline__ unsigned short f2bfu(float v) {
    __hip_bfloat16 b = __float2bfloat16(v);
    return *(unsigned short*)&b;
}
__device__ __forceinline__ unsigned pack2(float lo, float hi) {
    return (unsigned)f2bfu(lo) | ((unsigned)f2bfu(hi) << 16);
}

// ---- frontA: weight prep (fragment-linear layouts) + att projections ----
__global__ __launch_bounds__(256) void k_frontA(const float* __restrict__ W1,
                                                const float* __restrict__ W2,
                                                const float* __restrict__ atts1,
                                                const float* __restrict__ attd1,
                                                unsigned short* __restrict__ w1p,
                                                unsigned short* __restrict__ w2p,
                                                float* __restrict__ wproj) {
    int b = blockIdx.x;
    int t = threadIdx.x;
    if (b < 256) {                     // w1ps: c=b (out col), k=t
        if (t < K1P) {
            float v = (t < IN_CH) ? W1[t * C1 + b] : 0.f;
            int h = b >> 6, jj = (b >> 4) & 3, l15 = b & 15;
            int kk = t >> 5, quad = (t >> 3) & 3, e = t & 7;
            int f = (h * 4 + jj) * 2 + kk;
            w1p[(f * 64 + l15 * 4 + quad) * 8 + e] = f2bfu(v);
        }
    } else if (b < 384) {              // w2ps: c2=b-256 (out col), k=t
        int n = b - 256;
        int j = n >> 4, l15 = n & 15;
        int k0 = t >> 5, quad = (t >> 3) & 3, e = t & 7;
        int f = j * 8 + k0;
        w2p[(f * 64 + l15 * 4 + quad) * 8 + e] = f2bfu(W2[t * C2 + n]);
    } else {                           // att projections through W1
        int k = t >> 2, h = t & 3;
        float s = 0.f, dd = 0.f;
        if (k < IN_CH) {
            for (int j = 0; j < 64; ++j) {
                float wv = W1[k * C1 + h * 64 + j];
                s  += wv * atts1[h * 64 + j];
                dd += wv * attd1[h * 64 + j];
            }
        }
        wproj[t] = s;
        wproj[256 + t] = dd;
    }
}

// ---- mid: pass-1 bucket partition (LDS histogram, 1 global atomic/bucket/block)
//      + layer-1 logits (4 nodes/wave, float4 channels, width-16 reduce) ----
__global__ __launch_bounds__(256) void k_mid(const int* __restrict__ src,
                                             const int* __restrict__ dst,
                                             int* __restrict__ bcnt,
                                             uint2* __restrict__ ebuf,
                                             const float* __restrict__ x,
                                             const float* __restrict__ wproj,
                                             unsigned short* __restrict__ xbf,
                                             float* __restrict__ a_s,
                                             float* __restrict__ a_d) {
    __shared__ int lhist[NBUCK];
    __shared__ int lbase[NBUCK];
    int b = blockIdx.x;
    int t = threadIdx.x;
    if (b < NBUILD) {                  // bucket partition, 16 edges/thread
        if (t < NBUCK) lhist[t] = 0;
        __syncthreads();
        int j0 = (b * 256 + t) * 16;
        int s[16], d[16], bk[16], lp[16];
        bool v[16];
#pragma unroll
        for (int k = 0; k < 16; ++k) {
            int j = j0 + k;
            v[k] = j < E_TOT;
            if (v[k]) {
                if (j < N_EDGES) { s[k] = src[j]; d[k] = dst[j]; }
                else             { s[k] = d[k] = j - N_EDGES; }
                bk[k] = d[k] >> 8;
            }
        }
#pragma unroll
        for (int k = 0; k < 16; ++k)
            if (v[k]) lp[k] = atomicAdd(&lhist[bk[k]], 1);
        __syncthreads();
        if (t < NBUCK) lbase[t] = atomicAdd(&bcnt[t], lhist[t]);
        __syncthreads();
#pragma unroll
        for (int k = 0; k < 16; ++k)
            if (v[k])
                ebuf[(size_t)bk[k] * BCAP + lbase[bk[k]] + lp[k]] =
                    make_uint2((unsigned)s[k], (unsigned)d[k]);
    } else {                           // layer-1 logits + x -> bf16 cast
        int wave = t >> 6, lane = t & 63;
        int q = lane >> 4, hl = lane & 15;
        int n = (b - NBUILD) * 16 + wave * 4 + q;
        float xa[4] = {0.f, 0.f, 0.f, 0.f};
        const float* xr = x + (size_t)n * IN_CH + hl * 4;
        if (hl < 14) {
            float4 xv = *(const float4*)xr;
            xa[0] = xv.x; xa[1] = xv.y; xa[2] = xv.z; xa[3] = xv.w;
        } else if (hl == 14) {
            xa[0] = xr[0]; xa[1] = xr[1];
        }
        ((uint2*)xbf)[n * 16 + hl] = make_uint2(pack2(xa[0], xa[1]), pack2(xa[2], xa[3]));
        float ps[4] = {0.f, 0.f, 0.f, 0.f}, pd[4] = {0.f, 0.f, 0.f, 0.f};
#pragma unroll
        for (int cc = 0; cc < 4; ++cc) {
            int c = hl * 4 + cc;
            float4 wsv = *(const float4*)(wproj + c * 4);
            float4 wdv = *(const float4*)(wproj + 256 + c * 4);
            ps[0] += xa[cc] * wsv.x; ps[1] += xa[cc] * wsv.y;
            ps[2] += xa[cc] * wsv.z; ps[3] += xa[cc] * wsv.w;
            pd[0] += xa[cc] * wdv.x; pd[1] += xa[cc] * wdv.y;
            pd[2] += xa[cc] * wdv.z; pd[3] += xa[cc] * wdv.w;
        }
#pragma unroll
        for (int o = 8; o > 0; o >>= 1) {
#pragma unroll
            for (int r = 0; r < 4; ++r) {
                ps[r] += __shfl_down(ps[r], o, 16);
                pd[r] += __shfl_down(pd[r], o, 16);
            }
        }
        if (hl == 0) {
            *(float4*)(a_s + n * 4) = make_float4(ps[0], ps[1], ps[2], ps[3]);
            *(float4*)(a_d + n * 4) = make_float4(pd[0], pd[1], pd[2], pd[3]);
        }
    }
}

// ---- scat: pass-2 per-bucket scatter. One block per 256-node dst range;
// degree counters in LDS (zero global atomics), slots writes L2-local (64KB window).
__global__ __launch_bounds__(256) void k_scat(const int* __restrict__ bcnt,
                                              const uint2* __restrict__ ebuf,
                                              int* __restrict__ deg,
                                              int* __restrict__ slots) {
    __shared__ int ldeg[256];
    int blk = blockIdx.x, t = threadIdx.x;
    ldeg[t] = 0;
    __syncthreads();
    int cnt = bcnt[blk];
    const uint2* eb = ebuf + (size_t)blk * BCAP;
    int base = 0;
    for (; base + 1024 <= cnt; base += 1024) {
        uint2 e[4];
#pragma unroll
        for (int k = 0; k < 4; ++k) e[k] = eb[base + k * 256 + t];
#pragma unroll
        for (int k = 0; k < 4; ++k) {
            int pos = atomicAdd(&ldeg[e[k].y & 255], 1);
            slots[((int)e[k].y << 6) + pos] = (int)e[k].x;
        }
    }
    for (int i = base + t; i < cnt; i += 256) {
        uint2 e = eb[i];
        int pos = atomicAdd(&ldeg[e.y & 255], 1);
        slots[((int)e.y << 6) + pos] = (int)e.x;
    }
    __syncthreads();
    int g = (blk << 8) + t;
    if (g < N_NODES) deg[g] = ldeg[t];
}

// ---------------- layer 1 aggregate: 4 nodes/wave, masked uniform loop -------------
// No scalar tail: ceil(deg/8) full-width iterations; invalid lanes contribute 0 via
// cndmask (slot index clamped &0xFFFF stays inside workspace). Next iteration's slot
// indices are prefetched while the current FMA block runs, hiding the slots->gather
// dependency.
__global__ __launch_bounds__(256) void k_l1_agg(const int* __restrict__ degv,
                                                const int* __restrict__ slots,
                                                const float* __restrict__ a_s,
                                                const float* __restrict__ a_d,
                                                const uint2* __restrict__ xbf,
                                                unsigned short* __restrict__ xagg) {
    int t = threadIdx.x;
    int wave = t >> 6, lane = t & 63;
    int q = lane >> 4, hl = lane & 15;
    int d = blockIdx.x * 16 + wave * 4 + q;          // 3125*16 = 50000 exact
    int beg = d << 6;
    int dg = degv[d];
    float4 ad = *(const float4*)(a_d + d * 4);
    float z0 = 0.f, z1 = 0.f, z2 = 0.f, z3 = 0.f;
    float a0[4] = {0.f, 0.f, 0.f, 0.f};
    float a1[4] = {0.f, 0.f, 0.f, 0.f};
    float a2[4] = {0.f, 0.f, 0.f, 0.f};
    float a3[4] = {0.f, 0.f, 0.f, 0.f};
    int nit = (dg + 7) >> 3;
    int s[8];
#pragma unroll
    for (int k = 0; k < 8; ++k) s[k] = slots[beg + k] & 0xFFFF;
    for (int it = 0; it < nit; ++it) {
        int ibase = it * 8;
        int sn[8];
        int nb = (ibase + 8) & 63;                   // stays inside the 64-slot bucket
#pragma unroll
        for (int k = 0; k < 8; ++k) sn[k] = slots[beg + nb + k] & 0xFFFF;
        uint2 u[8]; float4 as[8];
#pragma unroll
        for (int k = 0; k < 8; ++k) u[k] = xbf[s[k] * 16 + hl];
#pragma unroll
        for (int k = 0; k < 8; ++k) as[k] = *(const float4*)(a_s + s[k] * 4);
#pragma unroll
        for (int k = 0; k < 8; ++k) {
            bool val = (ibase + k) < dg;
            float e0h = val ? __expf(leaky(as[k].x + ad.x)) : 0.f;
            float e1h = val ? __expf(leaky(as[k].y + ad.y)) : 0.f;
            float e2h = val ? __expf(leaky(as[k].z + ad.z)) : 0.f;
            float e3h = val ? __expf(leaky(as[k].w + ad.w)) : 0.f;
            z0 += e0h; z1 += e1h; z2 += e2h; z3 += e3h;
            float c0 = lo16(u[k].x), c1 = hi16(u[k].x);
            float c2 = lo16(u[k].y), c3 = hi16(u[k].y);
            a0[0] += e0h * c0; a0[1] += e0h * c1; a0[2] += e0h * c2; a0[3] += e0h * c3;
            a1[0] += e1h * c0; a1[1] += e1h * c1; a1[2] += e1h * c2; a1[3] += e1h * c3;
            a2[0] += e2h * c0; a2[1] += e2h * c1; a2[2] += e2h * c2; a2[3] += e2h * c3;
            a3[0] += e3h * c0; a3[1] += e3h * c1; a3[2] += e3h * c2; a3[3] += e3h * c3;
        }
#pragma unroll
        for (int k = 0; k < 8; ++k) s[k] = sn[k];
    }
    float i0 = 1.f / z0, i1 = 1.f / z1, i2 = 1.f / z2, i3 = 1.f / z3;
    // fragment-linear store: hl -> (kk, qd, half); node d -> (tile T, row r)
    int T = d >> 4, r = d & 15;
    int kk = hl >> 3, qd = (hl >> 1) & 3, half = hl & 1;
    uint2* xo = (uint2*)xagg;
    int base = (((T * 8 + kk) * 64) + r * 4 + qd) * 2 + half;   // head 0; +256/head
    xo[base +   0] = make_uint2(pack2(a0[0] * i0, a0[1] * i0), pack2(a0[2] * i0, a0[3] * i0));
    xo[base + 256] = make_uint2(pack2(a1[0] * i1, a1[1] * i1), pack2(a1[2] * i1, a1[3] * i1));
    xo[base + 512] = make_uint2(pack2(a2[0] * i2, a2[1] * i2), pack2(a2[2] * i2, a2[3] * i2));
    xo[base + 768] = make_uint2(pack2(a3[0] * i3, a3[1] * i3), pack2(a3[2] * i3, a3[3] * i3));
}

// ---------------- fused layer-1+2 GEMM: xagg -> h1 (LDS) -> h2 + att logits ---------
__global__ __launch_bounds__(256) void k_gemm12(const unsigned short* __restrict__ xagg,
                                                const unsigned short* __restrict__ w1p,
                                                const float* __restrict__ b1v,
                                                const unsigned short* __restrict__ w2p,
                                                const float* __restrict__ atts,
                                                const float* __restrict__ attd,
                                                unsigned short* __restrict__ h2bf,
                                                float* __restrict__ a_s,
                                                float* __restrict__ a_d) {
    __shared__ unsigned short hlds[4][16][264];   // layer-1 out; reused as h2 scratch
    int t = threadIdx.x;
    int wave = t >> 6, lane = t & 63;
    int T = blockIdx.x * 4 + wave;
    int m0 = T * 16;
    int l15 = lane & 15, quad = lane >> 4;
    int fl = l15 * 4 + quad;                      // fragment-lane index
    bool active = m0 < N_NODES;

    if (active) {
        const short8* xf  = (const short8*)xagg + (size_t)T * 512 + fl;
        const short8* w1f = (const short8*)w1p + fl;
        short8 av[H1][2];
#pragma unroll
        for (int h = 0; h < H1; ++h) {
            av[h][0] = xf[(h * 2 + 0) * 64];
            av[h][1] = xf[(h * 2 + 1) * 64];
        }
#pragma unroll
        for (int h = 0; h < H1; ++h) {
            short8 wb0[4], wb1[4];
#pragma unroll
            for (int jj = 0; jj < 4; ++jj) {
                wb0[jj] = w1f[(((h * 4 + jj) * 2) + 0) * 64];
                wb1[jj] = w1f[(((h * 4 + jj) * 2) + 1) * 64];
            }
            f32x4 acc[4];
#pragma unroll
            for (int jj = 0; jj < 4; ++jj) {
                acc[jj] = (f32x4){0.f, 0.f, 0.f, 0.f};
                acc[jj] = __builtin_amdgcn_mfma_f32_16x16x32_bf16(av[h][0], wb0[jj], acc[jj], 0, 0, 0);
                acc[jj] = __builtin_amdgcn_mfma_f32_16x16x32_bf16(av[h][1], wb1[jj], acc[jj], 0, 0, 0);
            }
#pragma unroll
            for (int jj = 0; jj < 4; ++jj) {
                int c = h * 64 + jj * 16 + l15;
                float bb = b1v[c];
#pragma unroll
                for (int r = 0; r < 4; ++r)
                    hlds[wave][quad * 4 + r][c] = f2bfu(fmaxf(acc[jj][r] + bb, 0.f));
            }
        }
    }
    __syncthreads();
    if (!active) return;

    // layer-2 A fragments from LDS (pitch 264)
    short8 a2[8];
    const unsigned short* a2row = &hlds[wave][l15][0] + quad * 8;
#pragma unroll
    for (int k0 = 0; k0 < 8; ++k0) a2[k0] = *(const short8*)(a2row + k0 * 32);

    const short8* w2f = (const short8*)w2p + fl;
    unsigned short* scr = &hlds[wave][0][0];      // reused as [16][136] (16B-aligned pitch)
    float ps[4] = {0.f, 0.f, 0.f, 0.f}, pd[4] = {0.f, 0.f, 0.f, 0.f};
#pragma unroll
    for (int j = 0; j < 8; ++j) {
        short8 wb[8];
#pragma unroll
        for (int k0 = 0; k0 < 8; ++k0)
            wb[k0] = w2f[(j * 8 + k0) * 64];
        f32x4 acc = (f32x4){0.f, 0.f, 0.f, 0.f};
#pragma unroll
        for (int k0 = 0; k0 < 8; ++k0)
            acc = __builtin_amdgcn_mfma_f32_16x16x32_bf16(a2[k0], wb[k0], acc, 0, 0, 0);
        float as_ = atts[j * 16 + l15], ad_ = attd[j * 16 + l15];
#pragma unroll
        for (int r = 0; r < 4; ++r) {
            float v = acc[r];
            scr[(quad * 4 + r) * 136 + j * 16 + l15] = f2bfu(v);
            ps[r] += v * as_;
            pd[r] += v * ad_;
        }
    }
#pragma unroll
    for (int r = 0; r < 4; ++r) {
#pragma unroll
        for (int o = 8; o > 0; o >>= 1) {
            ps[r] += __shfl_down(ps[r], o, 16);
            pd[r] += __shfl_down(pd[r], o, 16);
        }
        if (l15 == 0) {
            int n = m0 + quad * 4 + r;
            a_s[n] = ps[r];
            a_d[n] = pd[r];
        }
    }
    // coalesced h2bf store from wave-local scratch (DS ops are in-order per wave)
    int row = lane >> 2, seg = lane & 3;
#pragma unroll
    for (int c = 0; c < 4; ++c) {
        short8 v = *(const short8*)(scr + row * 136 + (c * 4 + seg) * 8);
        *(short8*)(h2bf + (size_t)(m0 + row) * C2 + (c * 4 + seg) * 8) = v;
    }
}

// ---------------- layer 2 aggregate + pool: 2 nodes/wave, balanced + masked --------
__global__ __launch_bounds__(256) void k_l2_aggpool(const int* __restrict__ degv,
                                                    const int* __restrict__ slots,
                                                    const float* __restrict__ a_s,
                                                    const float* __restrict__ a_d,
                                                    const unsigned short* __restrict__ h2bf,
                                                    const float* __restrict__ b2,
                                                    const int* __restrict__ batch,
                                                    float* __restrict__ pooled) {
    __shared__ float sacc[8][C2];
    __shared__ int sg[8];
    __shared__ int sdeg[8];
    __shared__ int perm[8];
    int t = threadIdx.x;
    int wave = t >> 6, lane = t & 63;
    int half = lane >> 5, hl = lane & 31;
    if (t < 8) {
        sdeg[t] = degv[blockIdx.x * 8 + t];
        sg[t] = batch[blockIdx.x * 8 + t];
    }
    __syncthreads();
    if (t < 8) {
        int dgi = sdeg[t], r = 0;
#pragma unroll
        for (int j = 0; j < 8; ++j) {
            int dj = sdeg[j];
            r += (dj < dgi) || (dj == dgi && j < t);
        }
        perm[r] = t;
    }
    __syncthreads();
    int nodeIdx = wave * 2 + half;
    int loc = perm[nodeIdx];
    int d = blockIdx.x * 8 + loc;
    int beg = d << 6;
    int dg = sdeg[loc];
    float ad = a_d[d];
    const uint2* rows = (const uint2*)h2bf;
    float a0 = 0.f, a1 = 0.f, a2 = 0.f, a3 = 0.f, z = 0.f;
    int nit = (dg + 7) >> 3;
    int s[8];
#pragma unroll
    for (int k = 0; k < 8; ++k) s[k] = slots[beg + k] & 0xFFFF;
    for (int it = 0; it < nit; ++it) {
        int ibase = it * 8;
        int sn[8];
        int nb = (ibase + 8) & 63;
#pragma unroll
        for (int k = 0; k < 8; ++k) sn[k] = slots[beg + nb + k] & 0xFFFF;
        uint2 u[8]; float ex[8];
#pragma unroll
        for (int k = 0; k < 8; ++k) u[k] = rows[s[k] * 32 + hl];
#pragma unroll
        for (int k = 0; k < 8; ++k) {
            bool val = (ibase + k) < dg;
            ex[k] = val ? __expf(leaky(a_s[s[k]] + ad)) : 0.f;
        }
#pragma unroll
        for (int k = 0; k < 8; ++k) {
            z  += ex[k];
            a0 += ex[k] * lo16(u[k].x); a1 += ex[k] * hi16(u[k].x);
            a2 += ex[k] * lo16(u[k].y); a3 += ex[k] * hi16(u[k].y);
        }
#pragma unroll
        for (int k = 0; k < 8; ++k) s[k] = sn[k];
    }
    float inv = 1.f / z;
    int c = hl * 4;
    float4 bv = *(const float4*)(b2 + c);
    float v0 = fmaxf(a0 * inv + bv.x, 0.f);
    float v1 = fmaxf(a1 * inv + bv.y, 0.f);
    float v2 = fmaxf(a2 * inv + bv.z, 0.f);
    float v3 = fmaxf(a3 * inv + bv.w, 0.f);
    *(float4*)&sacc[loc][c] = make_float4(v0, v1, v2, v3);
    __syncthreads();
    if (t < C2) {
        float run = sacc[0][t];
        int gprev = sg[0];
#pragma unroll
        for (int j = 1; j < 8; ++j) {
            int gj = sg[j];
            float v = sacc[j][t];
            if (gj == gprev) {
                run += v;
            } else {
                atomicAdd(&pooled[gprev * C2 + t], run);
                run = v;
                gprev = gj;
            }
        }
        atomicAdd(&pooled[gprev * C2 + t], run);
    }
}

// ---------------- BN: cnt via binary search on sorted batch (no atomics) ----------
__global__ __launch_bounds__(512) void k_bn(const float* __restrict__ pooled,
                                            const int* __restrict__ batch,
                                            const float* __restrict__ gamma,
                                            const float* __restrict__ beta,
                                            float* __restrict__ out) {
    int c = blockIdx.x;
    int g = threadIdx.x;
    int lo = 0, hi = N_NODES;
    while (lo < hi) { int m = (lo + hi) >> 1; if (batch[m] < g) lo = m + 1; else hi = m; }
    int lo2 = lo, hi2 = N_NODES;
    while (lo2 < hi2) { int m = (lo2 + hi2) >> 1; if (batch[m] < g + 1) lo2 = m + 1; else hi2 = m; }
    float cntg = (float)(hi2 - lo);

    __shared__ float red[512];
    __shared__ float s_mu, s_var;
    float v = pooled[g * C2 + c] / fmaxf(cntg, 1.0f);
    red[g] = v;
    __syncthreads();
    for (int s = 256; s > 0; s >>= 1) {
        if (g < s) red[g] += red[g + s];
        __syncthreads();
    }
    if (g == 0) s_mu = red[0] * (1.0f / N_GRAPHS);
    __syncthreads();
    float dv = v - s_mu;
    red[g] = dv * dv;
    __syncthreads();
    for (int s = 256; s > 0; s >>= 1) {
        if (g < s) red[g] += red[g + s];
        __syncthreads();
    }
    if (g == 0) s_var = red[0] * (1.0f / N_GRAPHS);
    __syncthreads();
    out[g * C2 + c] = dv * rsqrtf(s_var + 1e-5f) * gamma[c] + beta[c];
}

extern "C" void kernel_launch(void* const* d_in, const int* in_sizes, int n_in,
                              void* d_out, int out_size, void* d_ws, size_t ws_size,
                              hipStream_t stream) {
    const float* x     = (const float*)d_in[0];
    const int*   eidx  = (const int*)d_in[1];
    const int*   batch = (const int*)d_in[2];
    const float* W1    = (const float*)d_in[3];
    const float* atts1 = (const float*)d_in[4];
    const float* attd1 = (const float*)d_in[5];
    const float* b1    = (const float*)d_in[6];
    const float* W2    = (const float*)d_in[7];
    const float* atts2 = (const float*)d_in[8];
    const float* attd2 = (const float*)d_in[9];
    const float* b2    = (const float*)d_in[10];
    const float* gamma = (const float*)d_in[11];
    const float* beta  = (const float*)d_in[12];
    float* out = (float*)d_out;
    float* ws  = (float*)d_ws;

    const int* src = eidx;
    const int* dst = eidx + N_EDGES;

    // workspace layout, float-element offsets (bf16 arrays use 2 shorts per float)
    const size_t o_xbf    = 0;           // 1,600,000
    const size_t o_xagg   = 1600000;     // 6,400,000 (pass-1 ebuf aliases here: 2,007,040)
    const size_t o_h2bf   = 8000000;     // 3,200,000
    const size_t o_w1p    = 11200000;    // 8,192
    const size_t o_w2p    = 11208192;    // 16,384
    const size_t o_wproj  = 11224576;    // 512
    const size_t o_as1    = 11225088;    // 200,000
    const size_t o_ad1    = 11425088;    // 200,000
    const size_t o_as2    = 11625088;    // 50,000
    const size_t o_ad2    = 11675088;    // 50,000
    const size_t o_slots  = 11725088;    // 3,200,000 (50000 * 64 ints)
    // ---- contiguous zero block from here ----
    const size_t o_deg    = 14925088;    // 50,000
    const size_t o_pool   = 14975088;    // 65,536
    const size_t o_bcnt   = 15040624;    // 256
    const size_t total    = 15040880;    // ~60 MB

    int* p_slots = (int*)(ws + o_slots);
    int* p_deg   = (int*)(ws + o_deg);
    int* p_bcnt  = (int*)(ws + o_bcnt);
    uint2* p_ebuf = (uint2*)(ws + o_xagg);          // aliases xagg (consumed before xagg write)
    unsigned short* p_xbf  = (unsigned short*)(ws + o_xbf);
    unsigned short* p_xagg = (unsigned short*)(ws + o_xagg);
    unsigned short* p_h2bf = (unsigned short*)(ws + o_h2bf);
    unsigned short* p_w1p  = (unsigned short*)(ws + o_w1p);
    unsigned short* p_w2p  = (unsigned short*)(ws + o_w2p);

    hipMemsetAsync(ws + o_deg, 0, (total - o_deg) * sizeof(float), stream);

    // ---- frontA: weights (fragment-linear) + att projections ----
    k_frontA<<<385, 256, 0, stream>>>(W1, W2, atts1, attd1,
                                      p_w1p, p_w2p, ws + o_wproj);
    // ---- mid: pass-1 bucket partition + layer-1 logits / x cast ----
    k_mid<<<NBUILD + NATT, 256, 0, stream>>>(src, dst, p_bcnt, p_ebuf,
                                             x, ws + o_wproj, p_xbf,
                                             ws + o_as1, ws + o_ad1);
    // ---- pass-2: per-bucket scatter (LDS degree counters) ----
    k_scat<<<NBUCK, 256, 0, stream>>>(p_bcnt, p_ebuf, p_deg, p_slots);

    const int nagg1 = N_NODES / 16;             // 3125: 4 waves x 4 nodes per block
    const int nagg2 = N_NODES / 8;              // 6250: 4 waves x 2 nodes per block
    const int nmfma = (N_NODES + 63) / 64;      // 782: 4 waves x 16 nodes per block

    // ---- layer 1 aggregate + fused GEMM chain ----
    k_l1_agg<<<nagg1, 256, 0, stream>>>(p_deg, p_slots, ws + o_as1, ws + o_ad1,
                                        (const uint2*)p_xbf, p_xagg);
    k_gemm12<<<nmfma, 256, 0, stream>>>(p_xagg, p_w1p, b1, p_w2p, atts2, attd2,
                                        p_h2bf, ws + o_as2, ws + o_ad2);

    // ---- layer 2 aggregate + pool ----
    k_l2_aggpool<<<nagg2, 256, 0, stream>>>(p_deg, p_slots, ws + o_as2, ws + o_ad2,
                                            p_h2bf, b2, batch, ws + o_pool);

    // ---- BN (cnt via binary search, no atomics) ----
    k_bn<<<C2, 512, 0, stream>>>(ws + o_pool, batch, gamma, beta, out);
}

// Round 9
// 250.388 us; speedup vs baseline: 1.0021x; 1.0021x over previous
//
#include <hip/hip_runtime.h>
#include <hip/hip_bf16.h>
#include <math.h>

#define N_NODES  50000
#define N_EDGES  800000
#define E_TOT    850000   // + self loops
#define N_GRAPHS 512
#define IN_CH    58
#define K1P      64       // padded K for layer-1 MFMA
#define C1       256      // HEADS1 * H = 4*64
#define H1       4
#define C2       128
#define NEG_SLOPE 0.2f
#define SLOT_CAP 64       // fixed bucket capacity; P(Poisson(17) > 63) < 1e-13
#define NBUILD   208      // ceil(850000 / (256*16)) -- 16 edges per thread
#define NATT     3125     // 50000 / 16 -- 4 waves x 4 nodes per block
#define NBUCK    196      // ceil(50000 / 256) dst-range buckets
#define BCAP     5120     // per-bucket capacity; mean 4352, sigma 66 -> +11.7 sigma

typedef __attribute__((ext_vector_type(8))) short short8;
typedef __attribute__((ext_vector_type(4))) float f32x4;

__device__ __forceinline__ float lo16(unsigned u) { return __uint_as_float(u << 16); }
__device__ __forceinline__ float hi16(unsigned u) { return __uint_as_float(u & 0xffff0000u); }
__device__ __forceinline__ float leaky(float e) { return e > 0.f ? e : NEG_SLOPE * e; }
__device__ __forceinline__ unsigned short f2bfu(float v) {
    __hip_bfloat16 b = __float2bfloat16(v);
    return *(unsigned short*)&b;
}
__device__ __forceinline__ unsigned pack2(float lo, float hi) {
    return (unsigned)f2bfu(lo) | ((unsigned)f2bfu(hi) << 16);
}

// ---- frontA: weight prep (fragment-linear layouts) + att projections ----
__global__ __launch_bounds__(256) void k_frontA(const float* __restrict__ W1,
                                                const float* __restrict__ W2,
                                                const float* __restrict__ atts1,
                                                const float* __restrict__ attd1,
                                                unsigned short* __restrict__ w1p,
                                                unsigned short* __restrict__ w2p,
                                                float* __restrict__ wproj) {
    int b = blockIdx.x;
    int t = threadIdx.x;
    if (b < 256) {                     // w1ps: c=b (out col), k=t
        if (t < K1P) {
            float v = (t < IN_CH) ? W1[t * C1 + b] : 0.f;
            int h = b >> 6, jj = (b >> 4) & 3, l15 = b & 15;
            int kk = t >> 5, quad = (t >> 3) & 3, e = t & 7;
            int f = (h * 4 + jj) * 2 + kk;
            w1p[(f * 64 + l15 * 4 + quad) * 8 + e] = f2bfu(v);
        }
    } else if (b < 384) {              // w2ps: c2=b-256 (out col), k=t
        int n = b - 256;
        int j = n >> 4, l15 = n & 15;
        int k0 = t >> 5, quad = (t >> 3) & 3, e = t & 7;
        int f = j * 8 + k0;
        w2p[(f * 64 + l15 * 4 + quad) * 8 + e] = f2bfu(W2[t * C2 + n]);
    } else {                           // att projections through W1
        int k = t >> 2, h = t & 3;
        float s = 0.f, dd = 0.f;
        if (k < IN_CH) {
            for (int j = 0; j < 64; ++j) {
                float wv = W1[k * C1 + h * 64 + j];
                s  += wv * atts1[h * 64 + j];
                dd += wv * attd1[h * 64 + j];
            }
        }
        wproj[t] = s;
        wproj[256 + t] = dd;
    }
}

// ---- mid: pass-1 bucket partition (LDS histogram, 1 global atomic/bucket/block)
//      + layer-1 logits (4 nodes/wave, float4 channels, width-16 reduce) ----
__global__ __launch_bounds__(256) void k_mid(const int* __restrict__ src,
                                             const int* __restrict__ dst,
                                             int* __restrict__ bcnt,
                                             uint2* __restrict__ ebuf,
                                             const float* __restrict__ x,
                                             const float* __restrict__ wproj,
                                             unsigned short* __restrict__ xbf,
                                             float* __restrict__ a_s,
                                             float* __restrict__ a_d) {
    __shared__ int lhist[NBUCK];
    __shared__ int lbase[NBUCK];
    int b = blockIdx.x;
    int t = threadIdx.x;
    if (b < NBUILD) {                  // bucket partition, 16 edges/thread
        if (t < NBUCK) lhist[t] = 0;
        __syncthreads();
        int j0 = (b * 256 + t) * 16;
        int s[16], d[16], bk[16], lp[16];
        bool v[16];
#pragma unroll
        for (int k = 0; k < 16; ++k) {
            int j = j0 + k;
            v[k] = j < E_TOT;
            if (v[k]) {
                if (j < N_EDGES) { s[k] = src[j]; d[k] = dst[j]; }
                else             { s[k] = d[k] = j - N_EDGES; }
                bk[k] = d[k] >> 8;
            }
        }
#pragma unroll
        for (int k = 0; k < 16; ++k)
            if (v[k]) lp[k] = atomicAdd(&lhist[bk[k]], 1);
        __syncthreads();
        if (t < NBUCK) lbase[t] = atomicAdd(&bcnt[t], lhist[t]);
        __syncthreads();
#pragma unroll
        for (int k = 0; k < 16; ++k)
            if (v[k])
                ebuf[(size_t)bk[k] * BCAP + lbase[bk[k]] + lp[k]] =
                    make_uint2((unsigned)s[k], (unsigned)d[k]);
    } else {                           // layer-1 logits + x -> bf16 cast
        int wave = t >> 6, lane = t & 63;
        int q = lane >> 4, hl = lane & 15;
        int n = (b - NBUILD) * 16 + wave * 4 + q;
        float xa[4] = {0.f, 0.f, 0.f, 0.f};
        const float* xr = x + (size_t)n * IN_CH + hl * 4;
        if (hl < 14) {
            float4 xv = *(const float4*)xr;
            xa[0] = xv.x; xa[1] = xv.y; xa[2] = xv.z; xa[3] = xv.w;
        } else if (hl == 14) {
            xa[0] = xr[0]; xa[1] = xr[1];
        }
        ((uint2*)xbf)[n * 16 + hl] = make_uint2(pack2(xa[0], xa[1]), pack2(xa[2], xa[3]));
        float ps[4] = {0.f, 0.f, 0.f, 0.f}, pd[4] = {0.f, 0.f, 0.f, 0.f};
#pragma unroll
        for (int cc = 0; cc < 4; ++cc) {
            int c = hl * 4 + cc;
            float4 wsv = *(const float4*)(wproj + c * 4);
            float4 wdv = *(const float4*)(wproj + 256 + c * 4);
            ps[0] += xa[cc] * wsv.x; ps[1] += xa[cc] * wsv.y;
            ps[2] += xa[cc] * wsv.z; ps[3] += xa[cc] * wsv.w;
            pd[0] += xa[cc] * wdv.x; pd[1] += xa[cc] * wdv.y;
            pd[2] += xa[cc] * wdv.z; pd[3] += xa[cc] * wdv.w;
        }
#pragma unroll
        for (int o = 8; o > 0; o >>= 1) {
#pragma unroll
            for (int r = 0; r < 4; ++r) {
                ps[r] += __shfl_down(ps[r], o, 16);
                pd[r] += __shfl_down(pd[r], o, 16);
            }
        }
        if (hl == 0) {
            *(float4*)(a_s + n * 4) = make_float4(ps[0], ps[1], ps[2], ps[3]);
            *(float4*)(a_d + n * 4) = make_float4(pd[0], pd[1], pd[2], pd[3]);
        }
    }
}

// ---- scat: pass-2 per-bucket scatter. One block per 256-node dst range;
// degree counters in LDS (zero global atomics), slots writes L2-local (64KB window).
__global__ __launch_bounds__(256) void k_scat(const int* __restrict__ bcnt,
                                              const uint2* __restrict__ ebuf,
                                              int* __restrict__ deg,
                                              int* __restrict__ slots) {
    __shared__ int ldeg[256];
    int blk = blockIdx.x, t = threadIdx.x;
    ldeg[t] = 0;
    __syncthreads();
    int cnt = bcnt[blk];
    const uint2* eb = ebuf + (size_t)blk * BCAP;
    int base = 0;
    for (; base + 1024 <= cnt; base += 1024) {
        uint2 e[4];
#pragma unroll
        for (int k = 0; k < 4; ++k) e[k] = eb[base + k * 256 + t];
#pragma unroll
        for (int k = 0; k < 4; ++k) {
            int pos = atomicAdd(&ldeg[e[k].y & 255], 1);
            slots[((int)e[k].y << 6) + pos] = (int)e[k].x;
        }
    }
    for (int i = base + t; i < cnt; i += 256) {
        uint2 e = eb[i];
        int pos = atomicAdd(&ldeg[e.y & 255], 1);
        slots[((int)e.y << 6) + pos] = (int)e.x;
    }
    __syncthreads();
    int g = (blk << 8) + t;
    if (g < N_NODES) deg[g] = ldeg[t];
}

// ---------------- layer 1 aggregate: 4 nodes/wave, masked uniform loop -------------
// Tail-free: ceil(deg/8) full-width iterations. Invalid lanes point at slot 0 (always
// valid -- self-loop guarantees deg>=1, and its row is already cache-hot from it 0),
// so masked gathers cost no HBM traffic. Weights masked to 0 keep numerics exact.
__global__ __launch_bounds__(256) void k_l1_agg(const int* __restrict__ degv,
                                                const int* __restrict__ slots,
                                                const float* __restrict__ a_s,
                                                const float* __restrict__ a_d,
                                                const uint2* __restrict__ xbf,
                                                unsigned short* __restrict__ xagg) {
    int t = threadIdx.x;
    int wave = t >> 6, lane = t & 63;
    int q = lane >> 4, hl = lane & 15;
    int d = blockIdx.x * 16 + wave * 4 + q;          // 3125*16 = 50000 exact
    int beg = d << 6;
    int dg = degv[d];
    float4 ad = *(const float4*)(a_d + d * 4);
    float z0 = 0.f, z1 = 0.f, z2 = 0.f, z3 = 0.f;
    float a0[4] = {0.f, 0.f, 0.f, 0.f};
    float a1[4] = {0.f, 0.f, 0.f, 0.f};
    float a2[4] = {0.f, 0.f, 0.f, 0.f};
    float a3[4] = {0.f, 0.f, 0.f, 0.f};
    int s0 = slots[beg];
    int nit = (dg + 7) >> 3;
    int s[8];
#pragma unroll
    for (int k = 0; k < 8; ++k) s[k] = (k < dg) ? slots[beg + k] : s0;
    for (int it = 0; it < nit; ++it) {
        int ibase = it * 8;
        int sn[8];
#pragma unroll
        for (int k = 0; k < 8; ++k) {
            int idx = ibase + 8 + k;
            int raw = slots[beg + (idx & 63)];
            sn[k] = (idx < dg) ? raw : s0;
        }
        uint2 u[8]; float4 as[8];
#pragma unroll
        for (int k = 0; k < 8; ++k) u[k] = xbf[s[k] * 16 + hl];
#pragma unroll
        for (int k = 0; k < 8; ++k) as[k] = *(const float4*)(a_s + s[k] * 4);
#pragma unroll
        for (int k = 0; k < 8; ++k) {
            bool val = (ibase + k) < dg;
            float e0h = val ? __expf(leaky(as[k].x + ad.x)) : 0.f;
            float e1h = val ? __expf(leaky(as[k].y + ad.y)) : 0.f;
            float e2h = val ? __expf(leaky(as[k].z + ad.z)) : 0.f;
            float e3h = val ? __expf(leaky(as[k].w + ad.w)) : 0.f;
            z0 += e0h; z1 += e1h; z2 += e2h; z3 += e3h;
            float c0 = lo16(u[k].x), c1 = hi16(u[k].x);
            float c2 = lo16(u[k].y), c3 = hi16(u[k].y);
            a0[0] += e0h * c0; a0[1] += e0h * c1; a0[2] += e0h * c2; a0[3] += e0h * c3;
            a1[0] += e1h * c0; a1[1] += e1h * c1; a1[2] += e1h * c2; a1[3] += e1h * c3;
            a2[0] += e2h * c0; a2[1] += e2h * c1; a2[2] += e2h * c2; a2[3] += e2h * c3;
            a3[0] += e3h * c0; a3[1] += e3h * c1; a3[2] += e3h * c2; a3[3] += e3h * c3;
        }
#pragma unroll
        for (int k = 0; k < 8; ++k) s[k] = sn[k];
    }
    float i0 = 1.f / z0, i1 = 1.f / z1, i2 = 1.f / z2, i3 = 1.f / z3;
    // fragment-linear store: hl -> (kk, qd, half); node d -> (tile T, row r)
    int T = d >> 4, r = d & 15;
    int kk = hl >> 3, qd = (hl >> 1) & 3, half = hl & 1;
    uint2* xo = (uint2*)xagg;
    int base = (((T * 8 + kk) * 64) + r * 4 + qd) * 2 + half;   // head 0; +256/head
    xo[base +   0] = make_uint2(pack2(a0[0] * i0, a0[1] * i0), pack2(a0[2] * i0, a0[3] * i0));
    xo[base + 256] = make_uint2(pack2(a1[0] * i1, a1[1] * i1), pack2(a1[2] * i1, a1[3] * i1));
    xo[base + 512] = make_uint2(pack2(a2[0] * i2, a2[1] * i2), pack2(a2[2] * i2, a2[3] * i2));
    xo[base + 768] = make_uint2(pack2(a3[0] * i3, a3[1] * i3), pack2(a3[2] * i3, a3[3] * i3));
}

// ---------------- fused layer-1+2 GEMM: xagg -> h1 (LDS) -> h2 + att logits ---------
__global__ __launch_bounds__(256) void k_gemm12(const unsigned short* __restrict__ xagg,
                                                const unsigned short* __restrict__ w1p,
                                                const float* __restrict__ b1v,
                                                const unsigned short* __restrict__ w2p,
                                                const float* __restrict__ atts,
                                                const float* __restrict__ attd,
                                                unsigned short* __restrict__ h2bf,
                                                float* __restrict__ a_s,
                                                float* __restrict__ a_d) {
    __shared__ unsigned short hlds[4][16][264];   // layer-1 out; reused as h2 scratch
    int t = threadIdx.x;
    int wave = t >> 6, lane = t & 63;
    int T = blockIdx.x * 4 + wave;
    int m0 = T * 16;
    int l15 = lane & 15, quad = lane >> 4;
    int fl = l15 * 4 + quad;                      // fragment-lane index
    bool active = m0 < N_NODES;

    if (active) {
        const short8* xf  = (const short8*)xagg + (size_t)T * 512 + fl;
        const short8* w1f = (const short8*)w1p + fl;
        short8 av[H1][2];
#pragma unroll
        for (int h = 0; h < H1; ++h) {
            av[h][0] = xf[(h * 2 + 0) * 64];
            av[h][1] = xf[(h * 2 + 1) * 64];
        }
#pragma unroll
        for (int h = 0; h < H1; ++h) {
            short8 wb0[4], wb1[4];
#pragma unroll
            for (int jj = 0; jj < 4; ++jj) {
                wb0[jj] = w1f[(((h * 4 + jj) * 2) + 0) * 64];
                wb1[jj] = w1f[(((h * 4 + jj) * 2) + 1) * 64];
            }
            f32x4 acc[4];
#pragma unroll
            for (int jj = 0; jj < 4; ++jj) {
                acc[jj] = (f32x4){0.f, 0.f, 0.f, 0.f};
                acc[jj] = __builtin_amdgcn_mfma_f32_16x16x32_bf16(av[h][0], wb0[jj], acc[jj], 0, 0, 0);
                acc[jj] = __builtin_amdgcn_mfma_f32_16x16x32_bf16(av[h][1], wb1[jj], acc[jj], 0, 0, 0);
            }
#pragma unroll
            for (int jj = 0; jj < 4; ++jj) {
                int c = h * 64 + jj * 16 + l15;
                float bb = b1v[c];
#pragma unroll
                for (int r = 0; r < 4; ++r)
                    hlds[wave][quad * 4 + r][c] = f2bfu(fmaxf(acc[jj][r] + bb, 0.f));
            }
        }
    }
    __syncthreads();
    if (!active) return;

    // layer-2 A fragments from LDS (pitch 264)
    short8 a2[8];
    const unsigned short* a2row = &hlds[wave][l15][0] + quad * 8;
#pragma unroll
    for (int k0 = 0; k0 < 8; ++k0) a2[k0] = *(const short8*)(a2row + k0 * 32);

    const short8* w2f = (const short8*)w2p + fl;
    unsigned short* scr = &hlds[wave][0][0];      // reused as [16][136] (16B-aligned pitch)
    float ps[4] = {0.f, 0.f, 0.f, 0.f}, pd[4] = {0.f, 0.f, 0.f, 0.f};
#pragma unroll
    for (int j = 0; j < 8; ++j) {
        short8 wb[8];
#pragma unroll
        for (int k0 = 0; k0 < 8; ++k0)
            wb[k0] = w2f[(j * 8 + k0) * 64];
        f32x4 acc = (f32x4){0.f, 0.f, 0.f, 0.f};
#pragma unroll
        for (int k0 = 0; k0 < 8; ++k0)
            acc = __builtin_amdgcn_mfma_f32_16x16x32_bf16(a2[k0], wb[k0], acc, 0, 0, 0);
        float as_ = atts[j * 16 + l15], ad_ = attd[j * 16 + l15];
#pragma unroll
        for (int r = 0; r < 4; ++r) {
            float v = acc[r];
            scr[(quad * 4 + r) * 136 + j * 16 + l15] = f2bfu(v);
            ps[r] += v * as_;
            pd[r] += v * ad_;
        }
    }
#pragma unroll
    for (int r = 0; r < 4; ++r) {
#pragma unroll
        for (int o = 8; o > 0; o >>= 1) {
            ps[r] += __shfl_down(ps[r], o, 16);
            pd[r] += __shfl_down(pd[r], o, 16);
        }
        if (l15 == 0) {
            int n = m0 + quad * 4 + r;
            a_s[n] = ps[r];
            a_d[n] = pd[r];
        }
    }
    // coalesced h2bf store from wave-local scratch (DS ops are in-order per wave)
    int row = lane >> 2, seg = lane & 3;
#pragma unroll
    for (int c = 0; c < 4; ++c) {
        short8 v = *(const short8*)(scr + row * 136 + (c * 4 + seg) * 8);
        *(short8*)(h2bf + (size_t)(m0 + row) * C2 + (c * 4 + seg) * 8) = v;
    }
}

// ---------------- layer 2 aggregate + pool: 2 nodes/wave, balanced + masked --------
__global__ __launch_bounds__(256) void k_l2_aggpool(const int* __restrict__ degv,
                                                    const int* __restrict__ slots,
                                                    const float* __restrict__ a_s,
                                                    const float* __restrict__ a_d,
                                                    const unsigned short* __restrict__ h2bf,
                                                    const float* __restrict__ b2,
                                                    const int* __restrict__ batch,
                                                    float* __restrict__ pooled) {
    __shared__ float sacc[8][C2];
    __shared__ int sg[8];
    __shared__ int sdeg[8];
    __shared__ int perm[8];
    int t = threadIdx.x;
    int wave = t >> 6, lane = t & 63;
    int half = lane >> 5, hl = lane & 31;
    if (t < 8) {
        sdeg[t] = degv[blockIdx.x * 8 + t];
        sg[t] = batch[blockIdx.x * 8 + t];
    }
    __syncthreads();
    if (t < 8) {
        int dgi = sdeg[t], r = 0;
#pragma unroll
        for (int j = 0; j < 8; ++j) {
            int dj = sdeg[j];
            r += (dj < dgi) || (dj == dgi && j < t);
        }
        perm[r] = t;
    }
    __syncthreads();
    int nodeIdx = wave * 2 + half;
    int loc = perm[nodeIdx];
    int d = blockIdx.x * 8 + loc;
    int beg = d << 6;
    int dg = sdeg[loc];
    float ad = a_d[d];
    const uint2* rows = (const uint2*)h2bf;
    float a0 = 0.f, a1 = 0.f, a2 = 0.f, a3 = 0.f, z = 0.f;
    int s0 = slots[beg];
    int nit = (dg + 7) >> 3;
    int s[8];
#pragma unroll
    for (int k = 0; k < 8; ++k) s[k] = (k < dg) ? slots[beg + k] : s0;
    for (int it = 0; it < nit; ++it) {
        int ibase = it * 8;
        int sn[8];
#pragma unroll
        for (int k = 0; k < 8; ++k) {
            int idx = ibase + 8 + k;
            int raw = slots[beg + (idx & 63)];
            sn[k] = (idx < dg) ? raw : s0;
        }
        uint2 u[8]; float ex[8];
#pragma unroll
        for (int k = 0; k < 8; ++k) u[k] = rows[s[k] * 32 + hl];
#pragma unroll
        for (int k = 0; k < 8; ++k) {
            bool val = (ibase + k) < dg;
            ex[k] = val ? __expf(leaky(a_s[s[k]] + ad)) : 0.f;
        }
#pragma unroll
        for (int k = 0; k < 8; ++k) {
            z  += ex[k];
            a0 += ex[k] * lo16(u[k].x); a1 += ex[k] * hi16(u[k].x);
            a2 += ex[k] * lo16(u[k].y); a3 += ex[k] * hi16(u[k].y);
        }
#pragma unroll
        for (int k = 0; k < 8; ++k) s[k] = sn[k];
    }
    float inv = 1.f / z;
    int c = hl * 4;
    float4 bv = *(const float4*)(b2 + c);
    float v0 = fmaxf(a0 * inv + bv.x, 0.f);
    float v1 = fmaxf(a1 * inv + bv.y, 0.f);
    float v2 = fmaxf(a2 * inv + bv.z, 0.f);
    float v3 = fmaxf(a3 * inv + bv.w, 0.f);
    *(float4*)&sacc[loc][c] = make_float4(v0, v1, v2, v3);
    __syncthreads();
    if (t < C2) {
        float run = sacc[0][t];
        int gprev = sg[0];
#pragma unroll
        for (int j = 1; j < 8; ++j) {
            int gj = sg[j];
            float v = sacc[j][t];
            if (gj == gprev) {
                run += v;
            } else {
                atomicAdd(&pooled[gprev * C2 + t], run);
                run = v;
                gprev = gj;
            }
        }
        atomicAdd(&pooled[gprev * C2 + t], run);
    }
}

// ---------------- BN: cnt via binary search on sorted batch (no atomics) ----------
__global__ __launch_bounds__(512) void k_bn(const float* __restrict__ pooled,
                                            const int* __restrict__ batch,
                                            const float* __restrict__ gamma,
                                            const float* __restrict__ beta,
                                            float* __restrict__ out) {
    int c = blockIdx.x;
    int g = threadIdx.x;
    int lo = 0, hi = N_NODES;
    while (lo < hi) { int m = (lo + hi) >> 1; if (batch[m] < g) lo = m + 1; else hi = m; }
    int lo2 = lo, hi2 = N_NODES;
    while (lo2 < hi2) { int m = (lo2 + hi2) >> 1; if (batch[m] < g + 1) lo2 = m + 1; else hi2 = m; }
    float cntg = (float)(hi2 - lo);

    __shared__ float red[512];
    __shared__ float s_mu, s_var;
    float v = pooled[g * C2 + c] / fmaxf(cntg, 1.0f);
    red[g] = v;
    __syncthreads();
    for (int s = 256; s > 0; s >>= 1) {
        if (g < s) red[g] += red[g + s];
        __syncthreads();
    }
    if (g == 0) s_mu = red[0] * (1.0f / N_GRAPHS);
    __syncthreads();
    float dv = v - s_mu;
    red[g] = dv * dv;
    __syncthreads();
    for (int s = 256; s > 0; s >>= 1) {
        if (g < s) red[g] += red[g + s];
        __syncthreads();
    }
    if (g == 0) s_var = red[0] * (1.0f / N_GRAPHS);
    __syncthreads();
    out[g * C2 + c] = dv * rsqrtf(s_var + 1e-5f) * gamma[c] + beta[c];
}

extern "C" void kernel_launch(void* const* d_in, const int* in_sizes, int n_in,
                              void* d_out, int out_size, void* d_ws, size_t ws_size,
                              hipStream_t stream) {
    const float* x     = (const float*)d_in[0];
    const int*   eidx  = (const int*)d_in[1];
    const int*   batch = (const int*)d_in[2];
    const float* W1    = (const float*)d_in[3];
    const float* atts1 = (const float*)d_in[4];
    const float* attd1 = (const float*)d_in[5];
    const float* b1    = (const float*)d_in[6];
    const float* W2    = (const float*)d_in[7];
    const float* atts2 = (const float*)d_in[8];
    const float* attd2 = (const float*)d_in[9];
    const float* b2    = (const float*)d_in[10];
    const float* gamma = (const float*)d_in[11];
    const float* beta  = (const float*)d_in[12];
    float* out = (float*)d_out;
    float* ws  = (float*)d_ws;

    const int* src = eidx;
    const int* dst = eidx + N_EDGES;

    // workspace layout, float-element offsets (bf16 arrays use 2 shorts per float)
    const size_t o_xbf    = 0;           // 1,600,000
    const size_t o_xagg   = 1600000;     // 6,400,000 (pass-1 ebuf aliases here: 2,007,040)
    const size_t o_h2bf   = 8000000;     // 3,200,000
    const size_t o_w1p    = 11200000;    // 8,192
    const size_t o_w2p    = 11208192;    // 16,384
    const size_t o_wproj  = 11224576;    // 512
    const size_t o_as1    = 11225088;    // 200,000
    const size_t o_ad1    = 11425088;    // 200,000
    const size_t o_as2    = 11625088;    // 50,000
    const size_t o_ad2    = 11675088;    // 50,000
    const size_t o_slots  = 11725088;    // 3,200,000 (50000 * 64 ints)
    // ---- contiguous zero block from here ----
    const size_t o_deg    = 14925088;    // 50,000
    const size_t o_pool   = 14975088;    // 65,536
    const size_t o_bcnt   = 15040624;    // 256
    const size_t total    = 15040880;    // ~60 MB

    int* p_slots = (int*)(ws + o_slots);
    int* p_deg   = (int*)(ws + o_deg);
    int* p_bcnt  = (int*)(ws + o_bcnt);
    uint2* p_ebuf = (uint2*)(ws + o_xagg);          // aliases xagg (consumed before xagg write)
    unsigned short* p_xbf  = (unsigned short*)(ws + o_xbf);
    unsigned short* p_xagg = (unsigned short*)(ws + o_xagg);
    unsigned short* p_h2bf = (unsigned short*)(ws + o_h2bf);
    unsigned short* p_w1p  = (unsigned short*)(ws + o_w1p);
    unsigned short* p_w2p  = (unsigned short*)(ws + o_w2p);

    hipMemsetAsync(ws + o_deg, 0, (total - o_deg) * sizeof(float), stream);

    // ---- frontA: weights (fragment-linear) + att projections ----
    k_frontA<<<385, 256, 0, stream>>>(W1, W2, atts1, attd1,
                                      p_w1p, p_w2p, ws + o_wproj);
    // ---- mid: pass-1 bucket partition + layer-1 logits / x cast ----
    k_mid<<<NBUILD + NATT, 256, 0, stream>>>(src, dst, p_bcnt, p_ebuf,
                                             x, ws + o_wproj, p_xbf,
                                             ws + o_as1, ws + o_ad1);
    // ---- pass-2: per-bucket scatter (LDS degree counters) ----
    k_scat<<<NBUCK, 256, 0, stream>>>(p_bcnt, p_ebuf, p_deg, p_slots);

    const int nagg1 = N_NODES / 16;             // 3125: 4 waves x 4 nodes per block
    const int nagg2 = N_NODES / 8;              // 6250: 4 waves x 2 nodes per block
    const int nmfma = (N_NODES + 63) / 64;      // 782: 4 waves x 16 nodes per block

    // ---- layer 1 aggregate + fused GEMM chain ----
    k_l1_agg<<<nagg1, 256, 0, stream>>>(p_deg, p_slots, ws + o_as1, ws + o_ad1,
                                        (const uint2*)p_xbf, p_xagg);
    k_gemm12<<<nmfma, 256, 0, stream>>>(p_xagg, p_w1p, b1, p_w2p, atts2, attd2,
                                        p_h2bf, ws + o_as2, ws + o_ad2);

    // ---- layer 2 aggregate + pool ----
    k_l2_aggpool<<<nagg2, 256, 0, stream>>>(p_deg, p_slots, ws + o_as2, ws + o_ad2,
                                            p_h2bf, b2, batch, ws + o_pool);

    // ---- BN (cnt via binary search, no atomics) ----
    k_bn<<<C2, 512, 0, stream>>>(ws + o_pool, batch, gamma, beta, out);
}

// Round 11
// 221.252 us; speedup vs baseline: 1.1341x; 1.1317x over previous
//
#include <hip/hip_runtime.h>
#include <hip/hip_bf16.h>
#include <math.h>

#define N_NODES  50000
#define N_EDGES  800000
#define E_TOT    850000   // + self loops
#define N_GRAPHS 512
#define IN_CH    58
#define K1P      64       // padded K for layer-1 MFMA
#define C1       256      // HEADS1 * H = 4*64
#define H1       4
#define C2       128
#define NEG_SLOPE 0.2f
#define SLOT_CAP 64       // fixed bucket capacity; P(Poisson(17) > 63) < 1e-13
#define NBUILD   208      // ceil(850000 / (256*16)) -- 16 edges per thread
#define NATT     3125     // 50000 / 16 -- 4 waves x 4 nodes per block
#define NBUCK    196      // ceil(50000 / 256) dst-range buckets
#define BCAP     5120     // per-bucket capacity; mean 4352, sigma 66 -> +11.7 sigma

typedef __attribute__((ext_vector_type(8))) short short8;
typedef __attribute__((ext_vector_type(4))) float f32x4;

__device__ __forceinline__ float lo16(unsigned u) { return __uint_as_float(u << 16); }
__device__ __forceinline__ float hi16(unsigned u) { return __uint_as_float(u & 0xffff0000u); }
__device__ __forceinline__ float leaky(float e) { return e > 0.f ? e : NEG_SLOPE * e; }
__device__ __forceinline__ unsigned short f2bfu(float v) {
    __hip_bfloat16 b = __float2bfloat16(v);
    return *(unsigned short*)&b;
}
__device__ __forceinline__ unsigned pack2(float lo, float hi) {
    return (unsigned)f2bfu(lo) | ((unsigned)f2bfu(hi) << 16);
}

// ---- frontA: weight prep (fragment-linear layouts) + att projections ----
__global__ __launch_bounds__(256) void k_frontA(const float* __restrict__ W1,
                                                const float* __restrict__ W2,
                                                const float* __restrict__ atts1,
                                                const float* __restrict__ attd1,
                                                unsigned short* __restrict__ w1p,
                                                unsigned short* __restrict__ w2p,
                                                float* __restrict__ wproj) {
    int b = blockIdx.x;
    int t = threadIdx.x;
    if (b < 256) {                     // w1ps: c=b (out col), k=t
        if (t < K1P) {
            float v = (t < IN_CH) ? W1[t * C1 + b] : 0.f;
            int h = b >> 6, jj = (b >> 4) & 3, l15 = b & 15;
            int kk = t >> 5, quad = (t >> 3) & 3, e = t & 7;
            int f = (h * 4 + jj) * 2 + kk;
            w1p[(f * 64 + l15 * 4 + quad) * 8 + e] = f2bfu(v);
        }
    } else if (b < 384) {              // w2ps: c2=b-256 (out col), k=t
        int n = b - 256;
        int j = n >> 4, l15 = n & 15;
        int k0 = t >> 5, quad = (t >> 3) & 3, e = t & 7;
        int f = j * 8 + k0;
        w2p[(f * 64 + l15 * 4 + quad) * 8 + e] = f2bfu(W2[t * C2 + n]);
    } else {                           // att projections through W1
        int k = t >> 2, h = t & 3;
        float s = 0.f, dd = 0.f;
        if (k < IN_CH) {
            for (int j = 0; j < 64; ++j) {
                float wv = W1[k * C1 + h * 64 + j];
                s  += wv * atts1[h * 64 + j];
                dd += wv * attd1[h * 64 + j];
            }
        }
        wproj[t] = s;
        wproj[256 + t] = dd;
    }
}

// ---- mid: pass-1 bucket partition (LDS histogram, 1 global atomic/bucket/block)
//      + layer-1 logits (4 nodes/wave, float4 channels, width-16 reduce) ----
__global__ __launch_bounds__(256) void k_mid(const int* __restrict__ src,
                                             const int* __restrict__ dst,
                                             int* __restrict__ bcnt,
                                             uint2* __restrict__ ebuf,
                                             const float* __restrict__ x,
                                             const float* __restrict__ wproj,
                                             unsigned short* __restrict__ xbf,
                                             float* __restrict__ a_s,
                                             float* __restrict__ a_d) {
    __shared__ int lhist[NBUCK];
    __shared__ int lbase[NBUCK];
    int b = blockIdx.x;
    int t = threadIdx.x;
    if (b < NBUILD) {                  // bucket partition, 16 edges/thread
        if (t < NBUCK) lhist[t] = 0;
        __syncthreads();
        int j0 = (b * 256 + t) * 16;
        int s[16], d[16], bk[16], lp[16];
        bool v[16];
#pragma unroll
        for (int k = 0; k < 16; ++k) {
            int j = j0 + k;
            v[k] = j < E_TOT;
            if (v[k]) {
                if (j < N_EDGES) { s[k] = src[j]; d[k] = dst[j]; }
                else             { s[k] = d[k] = j - N_EDGES; }
                bk[k] = d[k] >> 8;
            }
        }
#pragma unroll
        for (int k = 0; k < 16; ++k)
            if (v[k]) lp[k] = atomicAdd(&lhist[bk[k]], 1);
        __syncthreads();
        if (t < NBUCK) lbase[t] = atomicAdd(&bcnt[t], lhist[t]);
        __syncthreads();
#pragma unroll
        for (int k = 0; k < 16; ++k)
            if (v[k])
                ebuf[(size_t)bk[k] * BCAP + lbase[bk[k]] + lp[k]] =
                    make_uint2((unsigned)s[k], (unsigned)d[k]);
    } else {                           // layer-1 logits + x -> bf16 cast
        int wave = t >> 6, lane = t & 63;
        int q = lane >> 4, hl = lane & 15;
        int n = (b - NBUILD) * 16 + wave * 4 + q;
        float xa[4] = {0.f, 0.f, 0.f, 0.f};
        const float* xr = x + (size_t)n * IN_CH + hl * 4;
        if (hl < 14) {
            float4 xv = *(const float4*)xr;
            xa[0] = xv.x; xa[1] = xv.y; xa[2] = xv.z; xa[3] = xv.w;
        } else if (hl == 14) {
            xa[0] = xr[0]; xa[1] = xr[1];
        }
        ((uint2*)xbf)[n * 16 + hl] = make_uint2(pack2(xa[0], xa[1]), pack2(xa[2], xa[3]));
        float ps[4] = {0.f, 0.f, 0.f, 0.f}, pd[4] = {0.f, 0.f, 0.f, 0.f};
#pragma unroll
        for (int cc = 0; cc < 4; ++cc) {
            int c = hl * 4 + cc;
            float4 wsv = *(const float4*)(wproj + c * 4);
            float4 wdv = *(const float4*)(wproj + 256 + c * 4);
            ps[0] += xa[cc] * wsv.x; ps[1] += xa[cc] * wsv.y;
            ps[2] += xa[cc] * wsv.z; ps[3] += xa[cc] * wsv.w;
            pd[0] += xa[cc] * wdv.x; pd[1] += xa[cc] * wdv.y;
            pd[2] += xa[cc] * wdv.z; pd[3] += xa[cc] * wdv.w;
        }
#pragma unroll
        for (int o = 8; o > 0; o >>= 1) {
#pragma unroll
            for (int r = 0; r < 4; ++r) {
                ps[r] += __shfl_down(ps[r], o, 16);
                pd[r] += __shfl_down(pd[r], o, 16);
            }
        }
        if (hl == 0) {
            *(float4*)(a_s + n * 4) = make_float4(ps[0], ps[1], ps[2], ps[3]);
            *(float4*)(a_d + n * 4) = make_float4(pd[0], pd[1], pd[2], pd[3]);
        }
    }
}

// ---- scat: pass-2 per-bucket scatter. One block per 256-node dst range;
// degree counters in LDS (zero global atomics), slots writes L2-local (64KB window).
__global__ __launch_bounds__(256) void k_scat(const int* __restrict__ bcnt,
                                              const uint2* __restrict__ ebuf,
                                              int* __restrict__ deg,
                                              int* __restrict__ slots) {
    __shared__ int ldeg[256];
    int blk = blockIdx.x, t = threadIdx.x;
    ldeg[t] = 0;
    __syncthreads();
    int cnt = bcnt[blk];
    const uint2* eb = ebuf + (size_t)blk * BCAP;
    int base = 0;
    for (; base + 1024 <= cnt; base += 1024) {
        uint2 e[4];
#pragma unroll
        for (int k = 0; k < 4; ++k) e[k] = eb[base + k * 256 + t];
#pragma unroll
        for (int k = 0; k < 4; ++k) {
            int pos = atomicAdd(&ldeg[e[k].y & 255], 1);
            slots[((int)e[k].y << 6) + pos] = (int)e[k].x;
        }
    }
    for (int i = base + t; i < cnt; i += 256) {
        uint2 e = eb[i];
        int pos = atomicAdd(&ldeg[e.y & 255], 1);
        slots[((int)e.y << 6) + pos] = (int)e.x;
    }
    __syncthreads();
    int g = (blk << 8) + t;
    if (g < N_NODES) deg[g] = ldeg[t];
}

// ---------------- layer 1 aggregate: shfl-resident slots + weights ----------------
// Node's 64 slot entries live in registers spread over its 16 lanes (4/lane). Each
// lane computes exp-weights ONLY for its 4 owned edges (vs all edges before), z via
// one shfl_xor tree, weights pre-normalized. Main loop is pure shfl+gather+FMA:
// no exp, no divide, no a_s loads, no tail, no slot re-reads.
__global__ __launch_bounds__(256) void k_l1_agg(const int* __restrict__ degv,
                                                const int* __restrict__ slots,
                                                const float* __restrict__ a_s,
                                                const float* __restrict__ a_d,
                                                const uint2* __restrict__ xbf,
                                                unsigned short* __restrict__ xagg) {
    int t = threadIdx.x;
    int wave = t >> 6, lane = t & 63;
    int q = lane >> 4, hl = lane & 15;
    int d = blockIdx.x * 16 + wave * 4 + q;          // 3125*16 = 50000 exact
    int beg = d << 6;
    int dg = degv[d];
    float4 ad = *(const float4*)(a_d + d * 4);
    int s0 = slots[beg];
    // owned edges: e = g*16 + hl
    int sR[4];
    float w[4][4];                                    // [group][head]
#pragma unroll
    for (int g = 0; g < 4; ++g) {
        int idx = g * 16 + hl;
        bool val = idx < dg;
        int raw = val ? slots[beg + idx] : s0;
        sR[g] = raw;
        if (val) {
            float4 as = *(const float4*)(a_s + raw * 4);
            w[g][0] = __expf(leaky(as.x + ad.x));
            w[g][1] = __expf(leaky(as.y + ad.y));
            w[g][2] = __expf(leaky(as.z + ad.z));
            w[g][3] = __expf(leaky(as.w + ad.w));
        } else {
            w[g][0] = 0.f; w[g][1] = 0.f; w[g][2] = 0.f; w[g][3] = 0.f;
        }
    }
    float z[4];
#pragma unroll
    for (int h = 0; h < 4; ++h) z[h] = w[0][h] + w[1][h] + w[2][h] + w[3][h];
#pragma unroll
    for (int o = 8; o > 0; o >>= 1)
#pragma unroll
        for (int h = 0; h < 4; ++h) z[h] += __shfl_xor(z[h], o, 16);
#pragma unroll
    for (int h = 0; h < 4; ++h) {
        float iz = 1.f / z[h];
#pragma unroll
        for (int g = 0; g < 4; ++g) w[g][h] *= iz;
    }
    float a0[4] = {0.f, 0.f, 0.f, 0.f};
    float a1[4] = {0.f, 0.f, 0.f, 0.f};
    float a2[4] = {0.f, 0.f, 0.f, 0.f};
    float a3[4] = {0.f, 0.f, 0.f, 0.f};
#pragma unroll
    for (int g = 0; g < 4; ++g) {
        if (g * 16 < dg) {
            int sk[16];
#pragma unroll
            for (int kk = 0; kk < 16; ++kk) sk[kk] = __shfl(sR[g], kk, 16);
            uint2 u[16];
#pragma unroll
            for (int kk = 0; kk < 16; ++kk) u[kk] = xbf[sk[kk] * 16 + hl];
#pragma unroll
            for (int kk = 0; kk < 16; ++kk) {
                float w0 = __shfl(w[g][0], kk, 16);
                float w1 = __shfl(w[g][1], kk, 16);
                float w2 = __shfl(w[g][2], kk, 16);
                float w3 = __shfl(w[g][3], kk, 16);
                float c0 = lo16(u[kk].x), c1 = hi16(u[kk].x);
                float c2 = lo16(u[kk].y), c3 = hi16(u[kk].y);
                a0[0] += w0 * c0; a0[1] += w0 * c1; a0[2] += w0 * c2; a0[3] += w0 * c3;
                a1[0] += w1 * c0; a1[1] += w1 * c1; a1[2] += w1 * c2; a1[3] += w1 * c3;
                a2[0] += w2 * c0; a2[1] += w2 * c1; a2[2] += w2 * c2; a2[3] += w2 * c3;
                a3[0] += w3 * c0; a3[1] += w3 * c1; a3[2] += w3 * c2; a3[3] += w3 * c3;
            }
        }
    }
    // fragment-linear store (weights pre-normalized; no divide here)
    int T = d >> 4, r = d & 15;
    int kk = hl >> 3, qd = (hl >> 1) & 3, half = hl & 1;
    uint2* xo = (uint2*)xagg;
    int base = (((T * 8 + kk) * 64) + r * 4 + qd) * 2 + half;   // head 0; +256/head
    xo[base +   0] = make_uint2(pack2(a0[0], a0[1]), pack2(a0[2], a0[3]));
    xo[base + 256] = make_uint2(pack2(a1[0], a1[1]), pack2(a1[2], a1[3]));
    xo[base + 512] = make_uint2(pack2(a2[0], a2[1]), pack2(a2[2], a2[3]));
    xo[base + 768] = make_uint2(pack2(a3[0], a3[1]), pack2(a3[2], a3[3]));
}

// ---------------- fused layer-1+2 GEMM: xagg -> h1 (LDS) -> h2 + att logits ---------
__global__ __launch_bounds__(256) void k_gemm12(const unsigned short* __restrict__ xagg,
                                                const unsigned short* __restrict__ w1p,
                                                const float* __restrict__ b1v,
                                                const unsigned short* __restrict__ w2p,
                                                const float* __restrict__ atts,
                                                const float* __restrict__ attd,
                                                unsigned short* __restrict__ h2bf,
                                                float* __restrict__ a_s,
                                                float* __restrict__ a_d) {
    __shared__ unsigned short hlds[4][16][264];   // layer-1 out; reused as h2 scratch
    int t = threadIdx.x;
    int wave = t >> 6, lane = t & 63;
    int T = blockIdx.x * 4 + wave;
    int m0 = T * 16;
    int l15 = lane & 15, quad = lane >> 4;
    int fl = l15 * 4 + quad;                      // fragment-lane index
    bool active = m0 < N_NODES;

    if (active) {
        const short8* xf  = (const short8*)xagg + (size_t)T * 512 + fl;
        const short8* w1f = (const short8*)w1p + fl;
        short8 av[H1][2];
#pragma unroll
        for (int h = 0; h < H1; ++h) {
            av[h][0] = xf[(h * 2 + 0) * 64];
            av[h][1] = xf[(h * 2 + 1) * 64];
        }
#pragma unroll
        for (int h = 0; h < H1; ++h) {
            short8 wb0[4], wb1[4];
#pragma unroll
            for (int jj = 0; jj < 4; ++jj) {
                wb0[jj] = w1f[(((h * 4 + jj) * 2) + 0) * 64];
                wb1[jj] = w1f[(((h * 4 + jj) * 2) + 1) * 64];
            }
            f32x4 acc[4];
#pragma unroll
            for (int jj = 0; jj < 4; ++jj) {
                acc[jj] = (f32x4){0.f, 0.f, 0.f, 0.f};
                acc[jj] = __builtin_amdgcn_mfma_f32_16x16x32_bf16(av[h][0], wb0[jj], acc[jj], 0, 0, 0);
                acc[jj] = __builtin_amdgcn_mfma_f32_16x16x32_bf16(av[h][1], wb1[jj], acc[jj], 0, 0, 0);
            }
#pragma unroll
            for (int jj = 0; jj < 4; ++jj) {
                int c = h * 64 + jj * 16 + l15;
                float bb = b1v[c];
#pragma unroll
                for (int r = 0; r < 4; ++r)
                    hlds[wave][quad * 4 + r][c] = f2bfu(fmaxf(acc[jj][r] + bb, 0.f));
            }
        }
    }
    __syncthreads();
    if (!active) return;

    // layer-2 A fragments from LDS (pitch 264)
    short8 a2[8];
    const unsigned short* a2row = &hlds[wave][l15][0] + quad * 8;
#pragma unroll
    for (int k0 = 0; k0 < 8; ++k0) a2[k0] = *(const short8*)(a2row + k0 * 32);

    const short8* w2f = (const short8*)w2p + fl;
    unsigned short* scr = &hlds[wave][0][0];      // reused as [16][136] (16B-aligned pitch)
    float ps[4] = {0.f, 0.f, 0.f, 0.f}, pd[4] = {0.f, 0.f, 0.f, 0.f};
#pragma unroll
    for (int j = 0; j < 8; ++j) {
        short8 wb[8];
#pragma unroll
        for (int k0 = 0; k0 < 8; ++k0)
            wb[k0] = w2f[(j * 8 + k0) * 64];
        f32x4 acc = (f32x4){0.f, 0.f, 0.f, 0.f};
#pragma unroll
        for (int k0 = 0; k0 < 8; ++k0)
            acc = __builtin_amdgcn_mfma_f32_16x16x32_bf16(a2[k0], wb[k0], acc, 0, 0, 0);
        float as_ = atts[j * 16 + l15], ad_ = attd[j * 16 + l15];
#pragma unroll
        for (int r = 0; r < 4; ++r) {
            float v = acc[r];
            scr[(quad * 4 + r) * 136 + j * 16 + l15] = f2bfu(v);
            ps[r] += v * as_;
            pd[r] += v * ad_;
        }
    }
#pragma unroll
    for (int r = 0; r < 4; ++r) {
#pragma unroll
        for (int o = 8; o > 0; o >>= 1) {
            ps[r] += __shfl_down(ps[r], o, 16);
            pd[r] += __shfl_down(pd[r], o, 16);
        }
        if (l15 == 0) {
            int n = m0 + quad * 4 + r;
            a_s[n] = ps[r];
            a_d[n] = pd[r];
        }
    }
    // coalesced h2bf store from wave-local scratch (DS ops are in-order per wave)
    int row = lane >> 2, seg = lane & 3;
#pragma unroll
    for (int c = 0; c < 4; ++c) {
        short8 v = *(const short8*)(scr + row * 136 + (c * 4 + seg) * 8);
        *(short8*)(h2bf + (size_t)(m0 + row) * C2 + (c * 4 + seg) * 8) = v;
    }
}

// ---------------- layer 2 aggregate + pool: shfl-resident slots + weights ----------
// 32 lanes/node, 2 slots/lane resident; exp computed once per edge (by owner lane),
// z via shfl_xor tree, weights pre-normalized. Main loop: shfl+gather+FMA only.
// Deg-rank balancing kept (helped in R6/R7).
__global__ __launch_bounds__(256) void k_l2_aggpool(const int* __restrict__ degv,
                                                    const int* __restrict__ slots,
                                                    const float* __restrict__ a_s,
                                                    const float* __restrict__ a_d,
                                                    const unsigned short* __restrict__ h2bf,
                                                    const float* __restrict__ b2,
                                                    const int* __restrict__ batch,
                                                    float* __restrict__ pooled) {
    __shared__ float sacc[8][C2];
    __shared__ int sg[8];
    __shared__ int sdeg[8];
    __shared__ int perm[8];
    int t = threadIdx.x;
    int wave = t >> 6, lane = t & 63;
    int half = lane >> 5, hl = lane & 31;
    if (t < 8) {
        sdeg[t] = degv[blockIdx.x * 8 + t];
        sg[t] = batch[blockIdx.x * 8 + t];
    }
    __syncthreads();
    if (t < 8) {
        int dgi = sdeg[t], r = 0;
#pragma unroll
        for (int j = 0; j < 8; ++j) {
            int dj = sdeg[j];
            r += (dj < dgi) || (dj == dgi && j < t);
        }
        perm[r] = t;
    }
    __syncthreads();
    int nodeIdx = wave * 2 + half;
    int loc = perm[nodeIdx];
    int d = blockIdx.x * 8 + loc;
    int beg = d << 6;
    int dg = sdeg[loc];
    float ad = a_d[d];
    const uint2* rows = (const uint2*)h2bf;
    int s0 = slots[beg];
    // owned edges: e = g*32 + hl
    int sR[2]; float w[2];
#pragma unroll
    for (int g = 0; g < 2; ++g) {
        int idx = g * 32 + hl;
        bool val = idx < dg;
        int raw = val ? slots[beg + idx] : s0;
        sR[g] = raw;
        w[g] = val ? __expf(leaky(a_s[raw] + ad)) : 0.f;
    }
    float z = w[0] + w[1];
#pragma unroll
    for (int o = 16; o > 0; o >>= 1) z += __shfl_xor(z, o, 32);
    float iz = 1.f / z;
    w[0] *= iz; w[1] *= iz;
    float a0 = 0.f, a1 = 0.f, a2 = 0.f, a3 = 0.f;
#pragma unroll
    for (int m = 0; m < 4; ++m) {                 // chunk of 16 edges: e = m*16+kk
        if (m * 16 < dg) {
            const int g = m >> 1, off = (m & 1) * 16;
            int sk[16];
#pragma unroll
            for (int kk = 0; kk < 16; ++kk) sk[kk] = __shfl(sR[g], off + kk, 32);
            uint2 u[16];
#pragma unroll
            for (int kk = 0; kk < 16; ++kk) u[kk] = rows[sk[kk] * 32 + hl];
#pragma unroll
            for (int kk = 0; kk < 16; ++kk) {
                float wk = __shfl(w[g], off + kk, 32);
                a0 += wk * lo16(u[kk].x); a1 += wk * hi16(u[kk].x);
                a2 += wk * lo16(u[kk].y); a3 += wk * hi16(u[kk].y);
            }
        }
    }
    int c = hl * 4;
    float4 bv = *(const float4*)(b2 + c);
    float v0 = fmaxf(a0 + bv.x, 0.f);
    float v1 = fmaxf(a1 + bv.y, 0.f);
    float v2 = fmaxf(a2 + bv.z, 0.f);
    float v3 = fmaxf(a3 + bv.w, 0.f);
    *(float4*)&sacc[loc][c] = make_float4(v0, v1, v2, v3);
    __syncthreads();
    if (t < C2) {
        float run = sacc[0][t];
        int gprev = sg[0];
#pragma unroll
        for (int j = 1; j < 8; ++j) {
            int gj = sg[j];
            float v = sacc[j][t];
            if (gj == gprev) {
                run += v;
            } else {
                atomicAdd(&pooled[gprev * C2 + t], run);
                run = v;
                gprev = gj;
            }
        }
        atomicAdd(&pooled[gprev * C2 + t], run);
    }
}

// ---------------- BN: cnt via binary search on sorted batch (no atomics) ----------
__global__ __launch_bounds__(512) void k_bn(const float* __restrict__ pooled,
                                            const int* __restrict__ batch,
                                            const float* __restrict__ gamma,
                                            const float* __restrict__ beta,
                                            float* __restrict__ out) {
    int c = blockIdx.x;
    int g = threadIdx.x;
    int lo = 0, hi = N_NODES;
    while (lo < hi) { int m = (lo + hi) >> 1; if (batch[m] < g) lo = m + 1; else hi = m; }
    int lo2 = lo, hi2 = N_NODES;
    while (lo2 < hi2) { int m = (lo2 + hi2) >> 1; if (batch[m] < g + 1) lo2 = m + 1; else hi2 = m; }
    float cntg = (float)(hi2 - lo);

    __shared__ float red[512];
    __shared__ float s_mu, s_var;
    float v = pooled[g * C2 + c] / fmaxf(cntg, 1.0f);
    red[g] = v;
    __syncthreads();
    for (int s = 256; s > 0; s >>= 1) {
        if (g < s) red[g] += red[g + s];
        __syncthreads();
    }
    if (g == 0) s_mu = red[0] * (1.0f / N_GRAPHS);
    __syncthreads();
    float dv = v - s_mu;
    red[g] = dv * dv;
    __syncthreads();
    for (int s = 256; s > 0; s >>= 1) {
        if (g < s) red[g] += red[g + s];
        __syncthreads();
    }
    if (g == 0) s_var = red[0] * (1.0f / N_GRAPHS);
    __syncthreads();
    out[g * C2 + c] = dv * rsqrtf(s_var + 1e-5f) * gamma[c] + beta[c];
}

extern "C" void kernel_launch(void* const* d_in, const int* in_sizes, int n_in,
                              void* d_out, int out_size, void* d_ws, size_t ws_size,
                              hipStream_t stream) {
    const float* x     = (const float*)d_in[0];
    const int*   eidx  = (const int*)d_in[1];
    const int*   batch = (const int*)d_in[2];
    const float* W1    = (const float*)d_in[3];
    const float* atts1 = (const float*)d_in[4];
    const float* attd1 = (const float*)d_in[5];
    const float* b1    = (const float*)d_in[6];
    const float* W2    = (const float*)d_in[7];
    const float* atts2 = (const float*)d_in[8];
    const float* attd2 = (const float*)d_in[9];
    const float* b2    = (const float*)d_in[10];
    const float* gamma = (const float*)d_in[11];
    const float* beta  = (const float*)d_in[12];
    float* out = (float*)d_out;
    float* ws  = (float*)d_ws;

    const int* src = eidx;
    const int* dst = eidx + N_EDGES;

    // workspace layout, float-element offsets (bf16 arrays use 2 shorts per float)
    const size_t o_xbf    = 0;           // 1,600,000
    const size_t o_xagg   = 1600000;     // 6,400,000 (pass-1 ebuf aliases here: 2,007,040)
    const size_t o_h2bf   = 8000000;     // 3,200,000
    const size_t o_w1p    = 11200000;    // 8,192
    const size_t o_w2p    = 11208192;    // 16,384
    const size_t o_wproj  = 11224576;    // 512
    const size_t o_as1    = 11225088;    // 200,000
    const size_t o_ad1    = 11425088;    // 200,000
    const size_t o_as2    = 11625088;    // 50,000
    const size_t o_ad2    = 11675088;    // 50,000
    const size_t o_slots  = 11725088;    // 3,200,000 (50000 * 64 ints)
    // ---- contiguous zero block from here ----
    const size_t o_deg    = 14925088;    // 50,000
    const size_t o_pool   = 14975088;    // 65,536
    const size_t o_bcnt   = 15040624;    // 256
    const size_t total    = 15040880;    // ~60 MB

    int* p_slots = (int*)(ws + o_slots);
    int* p_deg   = (int*)(ws + o_deg);
    int* p_bcnt  = (int*)(ws + o_bcnt);
    uint2* p_ebuf = (uint2*)(ws + o_xagg);          // aliases xagg (consumed before xagg write)
    unsigned short* p_xbf  = (unsigned short*)(ws + o_xbf);
    unsigned short* p_xagg = (unsigned short*)(ws + o_xagg);
    unsigned short* p_h2bf = (unsigned short*)(ws + o_h2bf);
    unsigned short* p_w1p  = (unsigned short*)(ws + o_w1p);
    unsigned short* p_w2p  = (unsigned short*)(ws + o_w2p);

    hipMemsetAsync(ws + o_deg, 0, (total - o_deg) * sizeof(float), stream);

    // ---- frontA: weights (fragment-linear) + att projections ----
    k_frontA<<<385, 256, 0, stream>>>(W1, W2, atts1, attd1,
                                      p_w1p, p_w2p, ws + o_wproj);
    // ---- mid: pass-1 bucket partition + layer-1 logits / x cast ----
    k_mid<<<NBUILD + NATT, 256, 0, stream>>>(src, dst, p_bcnt, p_ebuf,
                                             x, ws + o_wproj, p_xbf,
                                             ws + o_as1, ws + o_ad1);
    // ---- pass-2: per-bucket scatter (LDS degree counters) ----
    k_scat<<<NBUCK, 256, 0, stream>>>(p_bcnt, p_ebuf, p_deg, p_slots);

    const int nagg1 = N_NODES / 16;             // 3125: 4 waves x 4 nodes per block
    const int nagg2 = N_NODES / 8;              // 6250: 4 waves x 2 nodes per block
    const int nmfma = (N_NODES + 63) / 64;      // 782: 4 waves x 16 nodes per block

    // ---- layer 1 aggregate + fused GEMM chain ----
    k_l1_agg<<<nagg1, 256, 0, stream>>>(p_deg, p_slots, ws + o_as1, ws + o_ad1,
                                        (const uint2*)p_xbf, p_xagg);
    k_gemm12<<<nmfma, 256, 0, stream>>>(p_xagg, p_w1p, b1, p_w2p, atts2, attd2,
                                        p_h2bf, ws + o_as2, ws + o_ad2);

    // ---- layer 2 aggregate + pool ----
    k_l2_aggpool<<<nagg2, 256, 0, stream>>>(p_deg, p_slots, ws + o_as2, ws + o_ad2,
                                            p_h2bf, b2, batch, ws + o_pool);

    // ---- BN (cnt via binary search, no atomics) ----
    k_bn<<<C2, 512, 0, stream>>>(ws + o_pool, batch, gamma, beta, out);
}

// Round 12
// 220.880 us; speedup vs baseline: 1.1360x; 1.0017x over previous
//
#include <hip/hip_runtime.h>
#include <hip/hip_bf16.h>
#include <math.h>

#define N_NODES  50000
#define N_EDGES  800000
#define E_TOT    850000   // + self loops
#define N_GRAPHS 512
#define IN_CH    58
#define K1P      64       // padded K for layer-1 MFMA
#define C1       256      // HEADS1 * H = 4*64
#define H1       4
#define C2       128
#define NEG_SLOPE 0.2f
#define SLOT_CAP 64       // fixed bucket capacity; P(Poisson(17) > 63) < 1e-13
#define NBUILD   208      // ceil(850000 / (256*16)) -- 16 edges per thread
#define NATT     3125     // 50000 / 16 -- 4 waves x 4 nodes per block
#define NBUCK    196      // ceil(50000 / 256) dst-range buckets
#define BCAP     5120     // per-bucket capacity; mean 4352, sigma 66 -> +11.7 sigma

typedef __attribute__((ext_vector_type(8))) short short8;
typedef __attribute__((ext_vector_type(4))) float f32x4;

__device__ __forceinline__ float lo16(unsigned u) { return __uint_as_float(u << 16); }
__device__ __forceinline__ float hi16(unsigned u) { return __uint_as_float(u & 0xffff0000u); }
__device__ __forceinline__ float leaky(float e) { return e > 0.f ? e : NEG_SLOPE * e; }
__device__ __forceinline__ unsigned short f2bfu(float v) {
    __hip_bfloat16 b = __float2bfloat16(v);
    return *(unsigned short*)&b;
}
__device__ __forceinline__ unsigned pack2(float lo, float hi) {
    return (unsigned)f2bfu(lo) | ((unsigned)f2bfu(hi) << 16);
}

// ---- frontA: weight prep (fragment-linear layouts) + att projections ----
__global__ __launch_bounds__(256) void k_frontA(const float* __restrict__ W1,
                                                const float* __restrict__ W2,
                                                const float* __restrict__ atts1,
                                                const float* __restrict__ attd1,
                                                unsigned short* __restrict__ w1p,
                                                unsigned short* __restrict__ w2p,
                                                float* __restrict__ wproj) {
    int b = blockIdx.x;
    int t = threadIdx.x;
    if (b < 256) {                     // w1ps: c=b (out col), k=t
        if (t < K1P) {
            float v = (t < IN_CH) ? W1[t * C1 + b] : 0.f;
            int h = b >> 6, jj = (b >> 4) & 3, l15 = b & 15;
            int kk = t >> 5, quad = (t >> 3) & 3, e = t & 7;
            int f = (h * 4 + jj) * 2 + kk;
            w1p[(f * 64 + l15 * 4 + quad) * 8 + e] = f2bfu(v);
        }
    } else if (b < 384) {              // w2ps: c2=b-256 (out col), k=t
        int n = b - 256;
        int j = n >> 4, l15 = n & 15;
        int k0 = t >> 5, quad = (t >> 3) & 3, e = t & 7;
        int f = j * 8 + k0;
        w2p[(f * 64 + l15 * 4 + quad) * 8 + e] = f2bfu(W2[t * C2 + n]);
    } else {                           // att projections through W1
        int k = t >> 2, h = t & 3;
        float s = 0.f, dd = 0.f;
        if (k < IN_CH) {
            for (int j = 0; j < 64; ++j) {
                float wv = W1[k * C1 + h * 64 + j];
                s  += wv * atts1[h * 64 + j];
                dd += wv * attd1[h * 64 + j];
            }
        }
        wproj[t] = s;
        wproj[256 + t] = dd;
    }
}

// ---- mid: pass-1 bucket partition (LDS histogram, 1 global atomic/bucket/block)
//      + layer-1 logits (4 nodes/wave, float4 channels, width-16 reduce) ----
__global__ __launch_bounds__(256) void k_mid(const int* __restrict__ src,
                                             const int* __restrict__ dst,
                                             int* __restrict__ bcnt,
                                             uint2* __restrict__ ebuf,
                                             const float* __restrict__ x,
                                             const float* __restrict__ wproj,
                                             unsigned short* __restrict__ xbf,
                                             float* __restrict__ a_s,
                                             float* __restrict__ a_d) {
    __shared__ int lhist[NBUCK];
    __shared__ int lbase[NBUCK];
    int b = blockIdx.x;
    int t = threadIdx.x;
    if (b < NBUILD) {                  // bucket partition, 16 edges/thread
        if (t < NBUCK) lhist[t] = 0;
        __syncthreads();
        int j0 = (b * 256 + t) * 16;
        int s[16], d[16], bk[16], lp[16];
        bool v[16];
#pragma unroll
        for (int k = 0; k < 16; ++k) {
            int j = j0 + k;
            v[k] = j < E_TOT;
            if (v[k]) {
                if (j < N_EDGES) { s[k] = src[j]; d[k] = dst[j]; }
                else             { s[k] = d[k] = j - N_EDGES; }
                bk[k] = d[k] >> 8;
            }
        }
#pragma unroll
        for (int k = 0; k < 16; ++k)
            if (v[k]) lp[k] = atomicAdd(&lhist[bk[k]], 1);
        __syncthreads();
        if (t < NBUCK) lbase[t] = atomicAdd(&bcnt[t], lhist[t]);
        __syncthreads();
#pragma unroll
        for (int k = 0; k < 16; ++k)
            if (v[k])
                ebuf[(size_t)bk[k] * BCAP + lbase[bk[k]] + lp[k]] =
                    make_uint2((unsigned)s[k], (unsigned)d[k]);
    } else {                           // layer-1 logits + x -> bf16 cast
        int wave = t >> 6, lane = t & 63;
        int q = lane >> 4, hl = lane & 15;
        int n = (b - NBUILD) * 16 + wave * 4 + q;
        float xa[4] = {0.f, 0.f, 0.f, 0.f};
        const float* xr = x + (size_t)n * IN_CH + hl * 4;
        if (hl < 14) {
            float4 xv = *(const float4*)xr;
            xa[0] = xv.x; xa[1] = xv.y; xa[2] = xv.z; xa[3] = xv.w;
        } else if (hl == 14) {
            xa[0] = xr[0]; xa[1] = xr[1];
        }
        ((uint2*)xbf)[n * 16 + hl] = make_uint2(pack2(xa[0], xa[1]), pack2(xa[2], xa[3]));
        float ps[4] = {0.f, 0.f, 0.f, 0.f}, pd[4] = {0.f, 0.f, 0.f, 0.f};
#pragma unroll
        for (int cc = 0; cc < 4; ++cc) {
            int c = hl * 4 + cc;
            float4 wsv = *(const float4*)(wproj + c * 4);
            float4 wdv = *(const float4*)(wproj + 256 + c * 4);
            ps[0] += xa[cc] * wsv.x; ps[1] += xa[cc] * wsv.y;
            ps[2] += xa[cc] * wsv.z; ps[3] += xa[cc] * wsv.w;
            pd[0] += xa[cc] * wdv.x; pd[1] += xa[cc] * wdv.y;
            pd[2] += xa[cc] * wdv.z; pd[3] += xa[cc] * wdv.w;
        }
#pragma unroll
        for (int o = 8; o > 0; o >>= 1) {
#pragma unroll
            for (int r = 0; r < 4; ++r) {
                ps[r] += __shfl_down(ps[r], o, 16);
                pd[r] += __shfl_down(pd[r], o, 16);
            }
        }
        if (hl == 0) {
            *(float4*)(a_s + n * 4) = make_float4(ps[0], ps[1], ps[2], ps[3]);
            *(float4*)(a_d + n * 4) = make_float4(pd[0], pd[1], pd[2], pd[3]);
        }
    }
}

// ---- scat: pass-2 per-bucket scatter. One block per 256-node dst range;
// degree counters in LDS (zero global atomics), slots writes L2-local (64KB window).
__global__ __launch_bounds__(256) void k_scat(const int* __restrict__ bcnt,
                                              const uint2* __restrict__ ebuf,
                                              int* __restrict__ deg,
                                              int* __restrict__ slots) {
    __shared__ int ldeg[256];
    int blk = blockIdx.x, t = threadIdx.x;
    ldeg[t] = 0;
    __syncthreads();
    int cnt = bcnt[blk];
    const uint2* eb = ebuf + (size_t)blk * BCAP;
    int base = 0;
    for (; base + 1024 <= cnt; base += 1024) {
        uint2 e[4];
#pragma unroll
        for (int k = 0; k < 4; ++k) e[k] = eb[base + k * 256 + t];
#pragma unroll
        for (int k = 0; k < 4; ++k) {
            int pos = atomicAdd(&ldeg[e[k].y & 255], 1);
            slots[((int)e[k].y << 6) + pos] = (int)e[k].x;
        }
    }
    for (int i = base + t; i < cnt; i += 256) {
        uint2 e = eb[i];
        int pos = atomicAdd(&ldeg[e.y & 255], 1);
        slots[((int)e.y << 6) + pos] = (int)e.x;
    }
    __syncthreads();
    int g = (blk << 8) + t;
    if (g < N_NODES) deg[g] = ldeg[t];
}

// ---------------- layer 1 aggregate: shfl-resident + 8-edge chunks + rank-balance ---
// Slots+weights register-resident (4/lane over 16 lanes), exp once per edge, z via
// shfl tree, pre-normalized. Gather in 8-edge chunks (16-chunks waste 31% of gathers
// at Poisson-17; 8-chunks waste 17%). Deg-rank balance within the 16-node block is
// now locality-free: perm stays in-tile (stores: T=blockIdx) and in-4KB (slot reads).
__global__ __launch_bounds__(256) void k_l1_agg(const int* __restrict__ degv,
                                                const int* __restrict__ slots,
                                                const float* __restrict__ a_s,
                                                const float* __restrict__ a_d,
                                                const uint2* __restrict__ xbf,
                                                unsigned short* __restrict__ xagg) {
    __shared__ int sdeg[16];
    __shared__ int perm[16];
    int t = threadIdx.x;
    int wave = t >> 6, lane = t & 63;
    int q = lane >> 4, hl = lane & 15;
    if (t < 16) sdeg[t] = degv[blockIdx.x * 16 + t];
    __syncthreads();
    if (t < 16) {
        int dgi = sdeg[t], r = 0;
#pragma unroll
        for (int j = 0; j < 16; ++j) {
            int dj = sdeg[j];
            r += (dj < dgi) || (dj == dgi && j < t);
        }
        perm[r] = t;
    }
    __syncthreads();
    int loc = perm[wave * 4 + q];
    int d = blockIdx.x * 16 + loc;
    int beg = d << 6;
    int dg = sdeg[loc];
    float4 ad = *(const float4*)(a_d + d * 4);
    int s0 = slots[beg];
    // owned edges: e = g*16 + hl
    int sR[4];
    float w[4][4];                                    // [group][head]
#pragma unroll
    for (int g = 0; g < 4; ++g) {
        int idx = g * 16 + hl;
        bool val = idx < dg;
        int raw = val ? slots[beg + idx] : s0;
        sR[g] = raw;
        if (val) {
            float4 as = *(const float4*)(a_s + raw * 4);
            w[g][0] = __expf(leaky(as.x + ad.x));
            w[g][1] = __expf(leaky(as.y + ad.y));
            w[g][2] = __expf(leaky(as.z + ad.z));
            w[g][3] = __expf(leaky(as.w + ad.w));
        } else {
            w[g][0] = 0.f; w[g][1] = 0.f; w[g][2] = 0.f; w[g][3] = 0.f;
        }
    }
    float z[4];
#pragma unroll
    for (int h = 0; h < 4; ++h) z[h] = w[0][h] + w[1][h] + w[2][h] + w[3][h];
#pragma unroll
    for (int o = 8; o > 0; o >>= 1)
#pragma unroll
        for (int h = 0; h < 4; ++h) z[h] += __shfl_xor(z[h], o, 16);
#pragma unroll
    for (int h = 0; h < 4; ++h) {
        float iz = 1.f / z[h];
#pragma unroll
        for (int g = 0; g < 4; ++g) w[g][h] *= iz;
    }
    float a0[4] = {0.f, 0.f, 0.f, 0.f};
    float a1[4] = {0.f, 0.f, 0.f, 0.f};
    float a2[4] = {0.f, 0.f, 0.f, 0.f};
    float a3[4] = {0.f, 0.f, 0.f, 0.f};
#pragma unroll
    for (int c = 0; c < 8; ++c) {                     // 8-edge chunks
        if (c * 8 < dg) {
            const int g = c >> 1, off = (c & 1) * 8;
            int sk[8];
#pragma unroll
            for (int kk = 0; kk < 8; ++kk) sk[kk] = __shfl(sR[g], off + kk, 16);
            uint2 u[8];
#pragma unroll
            for (int kk = 0; kk < 8; ++kk) u[kk] = xbf[sk[kk] * 16 + hl];
#pragma unroll
            for (int kk = 0; kk < 8; ++kk) {
                float w0 = __shfl(w[g][0], off + kk, 16);
                float w1 = __shfl(w[g][1], off + kk, 16);
                float w2 = __shfl(w[g][2], off + kk, 16);
                float w3 = __shfl(w[g][3], off + kk, 16);
                float c0 = lo16(u[kk].x), c1 = hi16(u[kk].x);
                float c2 = lo16(u[kk].y), c3 = hi16(u[kk].y);
                a0[0] += w0 * c0; a0[1] += w0 * c1; a0[2] += w0 * c2; a0[3] += w0 * c3;
                a1[0] += w1 * c0; a1[1] += w1 * c1; a1[2] += w1 * c2; a1[3] += w1 * c3;
                a2[0] += w2 * c0; a2[1] += w2 * c1; a2[2] += w2 * c2; a2[3] += w2 * c3;
                a3[0] += w3 * c0; a3[1] += w3 * c1; a3[2] += w3 * c2; a3[3] += w3 * c3;
            }
        }
    }
    // fragment-linear store (weights pre-normalized; no divide here)
    int T = d >> 4, r = d & 15;
    int kk = hl >> 3, qd = (hl >> 1) & 3, half = hl & 1;
    uint2* xo = (uint2*)xagg;
    int base = (((T * 8 + kk) * 64) + r * 4 + qd) * 2 + half;   // head 0; +256/head
    xo[base +   0] = make_uint2(pack2(a0[0], a0[1]), pack2(a0[2], a0[3]));
    xo[base + 256] = make_uint2(pack2(a1[0], a1[1]), pack2(a1[2], a1[3]));
    xo[base + 512] = make_uint2(pack2(a2[0], a2[1]), pack2(a2[2], a2[3]));
    xo[base + 768] = make_uint2(pack2(a3[0], a3[1]), pack2(a3[2], a3[3]));
}

// ---------------- fused layer-1+2 GEMM: xagg -> h1 (LDS) -> h2 + att logits ---------
__global__ __launch_bounds__(256) void k_gemm12(const unsigned short* __restrict__ xagg,
                                                const unsigned short* __restrict__ w1p,
                                                const float* __restrict__ b1v,
                                                const unsigned short* __restrict__ w2p,
                                                const float* __restrict__ atts,
                                                const float* __restrict__ attd,
                                                unsigned short* __restrict__ h2bf,
                                                float* __restrict__ a_s,
                                                float* __restrict__ a_d) {
    __shared__ unsigned short hlds[4][16][264];   // layer-1 out; reused as h2 scratch
    int t = threadIdx.x;
    int wave = t >> 6, lane = t & 63;
    int T = blockIdx.x * 4 + wave;
    int m0 = T * 16;
    int l15 = lane & 15, quad = lane >> 4;
    int fl = l15 * 4 + quad;                      // fragment-lane index
    bool active = m0 < N_NODES;

    if (active) {
        const short8* xf  = (const short8*)xagg + (size_t)T * 512 + fl;
        const short8* w1f = (const short8*)w1p + fl;
        short8 av[H1][2];
#pragma unroll
        for (int h = 0; h < H1; ++h) {
            av[h][0] = xf[(h * 2 + 0) * 64];
            av[h][1] = xf[(h * 2 + 1) * 64];
        }
#pragma unroll
        for (int h = 0; h < H1; ++h) {
            short8 wb0[4], wb1[4];
#pragma unroll
            for (int jj = 0; jj < 4; ++jj) {
                wb0[jj] = w1f[(((h * 4 + jj) * 2) + 0) * 64];
                wb1[jj] = w1f[(((h * 4 + jj) * 2) + 1) * 64];
            }
            f32x4 acc[4];
#pragma unroll
            for (int jj = 0; jj < 4; ++jj) {
                acc[jj] = (f32x4){0.f, 0.f, 0.f, 0.f};
                acc[jj] = __builtin_amdgcn_mfma_f32_16x16x32_bf16(av[h][0], wb0[jj], acc[jj], 0, 0, 0);
                acc[jj] = __builtin_amdgcn_mfma_f32_16x16x32_bf16(av[h][1], wb1[jj], acc[jj], 0, 0, 0);
            }
#pragma unroll
            for (int jj = 0; jj < 4; ++jj) {
                int c = h * 64 + jj * 16 + l15;
                float bb = b1v[c];
#pragma unroll
                for (int r = 0; r < 4; ++r)
                    hlds[wave][quad * 4 + r][c] = f2bfu(fmaxf(acc[jj][r] + bb, 0.f));
            }
        }
    }
    __syncthreads();
    if (!active) return;

    // layer-2 A fragments from LDS (pitch 264)
    short8 a2[8];
    const unsigned short* a2row = &hlds[wave][l15][0] + quad * 8;
#pragma unroll
    for (int k0 = 0; k0 < 8; ++k0) a2[k0] = *(const short8*)(a2row + k0 * 32);

    const short8* w2f = (const short8*)w2p + fl;
    unsigned short* scr = &hlds[wave][0][0];      // reused as [16][136] (16B-aligned pitch)
    float ps[4] = {0.f, 0.f, 0.f, 0.f}, pd[4] = {0.f, 0.f, 0.f, 0.f};
#pragma unroll
    for (int j = 0; j < 8; ++j) {
        short8 wb[8];
#pragma unroll
        for (int k0 = 0; k0 < 8; ++k0)
            wb[k0] = w2f[(j * 8 + k0) * 64];
        f32x4 acc = (f32x4){0.f, 0.f, 0.f, 0.f};
#pragma unroll
        for (int k0 = 0; k0 < 8; ++k0)
            acc = __builtin_amdgcn_mfma_f32_16x16x32_bf16(a2[k0], wb[k0], acc, 0, 0, 0);
        float as_ = atts[j * 16 + l15], ad_ = attd[j * 16 + l15];
#pragma unroll
        for (int r = 0; r < 4; ++r) {
            float v = acc[r];
            scr[(quad * 4 + r) * 136 + j * 16 + l15] = f2bfu(v);
            ps[r] += v * as_;
            pd[r] += v * ad_;
        }
    }
#pragma unroll
    for (int r = 0; r < 4; ++r) {
#pragma unroll
        for (int o = 8; o > 0; o >>= 1) {
            ps[r] += __shfl_down(ps[r], o, 16);
            pd[r] += __shfl_down(pd[r], o, 16);
        }
        if (l15 == 0) {
            int n = m0 + quad * 4 + r;
            a_s[n] = ps[r];
            a_d[n] = pd[r];
        }
    }
    // coalesced h2bf store from wave-local scratch (DS ops are in-order per wave)
    int row = lane >> 2, seg = lane & 3;
#pragma unroll
    for (int c = 0; c < 4; ++c) {
        short8 v = *(const short8*)(scr + row * 136 + (c * 4 + seg) * 8);
        *(short8*)(h2bf + (size_t)(m0 + row) * C2 + (c * 4 + seg) * 8) = v;
    }
}

// ---------------- layer 2 aggregate + pool: shfl-resident + 8-edge chunks ----------
__global__ __launch_bounds__(256) void k_l2_aggpool(const int* __restrict__ degv,
                                                    const int* __restrict__ slots,
                                                    const float* __restrict__ a_s,
                                                    const float* __restrict__ a_d,
                                                    const unsigned short* __restrict__ h2bf,
                                                    const float* __restrict__ b2,
                                                    const int* __restrict__ batch,
                                                    float* __restrict__ pooled) {
    __shared__ float sacc[8][C2];
    __shared__ int sg[8];
    __shared__ int sdeg[8];
    __shared__ int perm[8];
    int t = threadIdx.x;
    int wave = t >> 6, lane = t & 63;
    int half = lane >> 5, hl = lane & 31;
    if (t < 8) {
        sdeg[t] = degv[blockIdx.x * 8 + t];
        sg[t] = batch[blockIdx.x * 8 + t];
    }
    __syncthreads();
    if (t < 8) {
        int dgi = sdeg[t], r = 0;
#pragma unroll
        for (int j = 0; j < 8; ++j) {
            int dj = sdeg[j];
            r += (dj < dgi) || (dj == dgi && j < t);
        }
        perm[r] = t;
    }
    __syncthreads();
    int nodeIdx = wave * 2 + half;
    int loc = perm[nodeIdx];
    int d = blockIdx.x * 8 + loc;
    int beg = d << 6;
    int dg = sdeg[loc];
    float ad = a_d[d];
    const uint2* rows = (const uint2*)h2bf;
    int s0 = slots[beg];
    // owned edges: e = g*32 + hl
    int sR[2]; float w[2];
#pragma unroll
    for (int g = 0; g < 2; ++g) {
        int idx = g * 32 + hl;
        bool val = idx < dg;
        int raw = val ? slots[beg + idx] : s0;
        sR[g] = raw;
        w[g] = val ? __expf(leaky(a_s[raw] + ad)) : 0.f;
    }
    float z = w[0] + w[1];
#pragma unroll
    for (int o = 16; o > 0; o >>= 1) z += __shfl_xor(z, o, 32);
    float iz = 1.f / z;
    w[0] *= iz; w[1] *= iz;
    float a0 = 0.f, a1 = 0.f, a2 = 0.f, a3 = 0.f;
#pragma unroll
    for (int c8 = 0; c8 < 8; ++c8) {              // 8-edge chunks: e = c8*8 + kk
        if (c8 * 8 < dg) {
            const int g = c8 >> 2, off = (c8 & 3) * 8;
            int sk[8];
#pragma unroll
            for (int kk = 0; kk < 8; ++kk) sk[kk] = __shfl(sR[g], off + kk, 32);
            uint2 u[8];
#pragma unroll
            for (int kk = 0; kk < 8; ++kk) u[kk] = rows[sk[kk] * 32 + hl];
#pragma unroll
            for (int kk = 0; kk < 8; ++kk) {
                float wk = __shfl(w[g], off + kk, 32);
                a0 += wk * lo16(u[kk].x); a1 += wk * hi16(u[kk].x);
                a2 += wk * lo16(u[kk].y); a3 += wk * hi16(u[kk].y);
            }
        }
    }
    int c = hl * 4;
    float4 bv = *(const float4*)(b2 + c);
    float v0 = fmaxf(a0 + bv.x, 0.f);
    float v1 = fmaxf(a1 + bv.y, 0.f);
    float v2 = fmaxf(a2 + bv.z, 0.f);
    float v3 = fmaxf(a3 + bv.w, 0.f);
    *(float4*)&sacc[loc][c] = make_float4(v0, v1, v2, v3);
    __syncthreads();
    if (t < C2) {
        float run = sacc[0][t];
        int gprev = sg[0];
#pragma unroll
        for (int j = 1; j < 8; ++j) {
            int gj = sg[j];
            float v = sacc[j][t];
            if (gj == gprev) {
                run += v;
            } else {
                atomicAdd(&pooled[gprev * C2 + t], run);
                run = v;
                gprev = gj;
            }
        }
        atomicAdd(&pooled[gprev * C2 + t], run);
    }
}

// ---------------- BN: cnt via binary search on sorted batch (no atomics) ----------
__global__ __launch_bounds__(512) void k_bn(const float* __restrict__ pooled,
                                            const int* __restrict__ batch,
                                            const float* __restrict__ gamma,
                                            const float* __restrict__ beta,
                                            float* __restrict__ out) {
    int c = blockIdx.x;
    int g = threadIdx.x;
    int lo = 0, hi = N_NODES;
    while (lo < hi) { int m = (lo + hi) >> 1; if (batch[m] < g) lo = m + 1; else hi = m; }
    int lo2 = lo, hi2 = N_NODES;
    while (lo2 < hi2) { int m = (lo2 + hi2) >> 1; if (batch[m] < g + 1) lo2 = m + 1; else hi2 = m; }
    float cntg = (float)(hi2 - lo);

    __shared__ float red[512];
    __shared__ float s_mu, s_var;
    float v = pooled[g * C2 + c] / fmaxf(cntg, 1.0f);
    red[g] = v;
    __syncthreads();
    for (int s = 256; s > 0; s >>= 1) {
        if (g < s) red[g] += red[g + s];
        __syncthreads();
    }
    if (g == 0) s_mu = red[0] * (1.0f / N_GRAPHS);
    __syncthreads();
    float dv = v - s_mu;
    red[g] = dv * dv;
    __syncthreads();
    for (int s = 256; s > 0; s >>= 1) {
        if (g < s) red[g] += red[g + s];
        __syncthreads();
    }
    if (g == 0) s_var = red[0] * (1.0f / N_GRAPHS);
    __syncthreads();
    out[g * C2 + c] = dv * rsqrtf(s_var + 1e-5f) * gamma[c] + beta[c];
}

extern "C" void kernel_launch(void* const* d_in, const int* in_sizes, int n_in,
                              void* d_out, int out_size, void* d_ws, size_t ws_size,
                              hipStream_t stream) {
    const float* x     = (const float*)d_in[0];
    const int*   eidx  = (const int*)d_in[1];
    const int*   batch = (const int*)d_in[2];
    const float* W1    = (const float*)d_in[3];
    const float* atts1 = (const float*)d_in[4];
    const float* attd1 = (const float*)d_in[5];
    const float* b1    = (const float*)d_in[6];
    const float* W2    = (const float*)d_in[7];
    const float* atts2 = (const float*)d_in[8];
    const float* attd2 = (const float*)d_in[9];
    const float* b2    = (const float*)d_in[10];
    const float* gamma = (const float*)d_in[11];
    const float* beta  = (const float*)d_in[12];
    float* out = (float*)d_out;
    float* ws  = (float*)d_ws;

    const int* src = eidx;
    const int* dst = eidx + N_EDGES;

    // workspace layout, float-element offsets (bf16 arrays use 2 shorts per float)
    const size_t o_xbf    = 0;           // 1,600,000
    const size_t o_xagg   = 1600000;     // 6,400,000 (pass-1 ebuf aliases here: 2,007,040)
    const size_t o_h2bf   = 8000000;     // 3,200,000
    const size_t o_w1p    = 11200000;    // 8,192
    const size_t o_w2p    = 11208192;    // 16,384
    const size_t o_wproj  = 11224576;    // 512
    const size_t o_as1    = 11225088;    // 200,000
    const size_t o_ad1    = 11425088;    // 200,000
    const size_t o_as2    = 11625088;    // 50,000
    const size_t o_ad2    = 11675088;    // 50,000
    const size_t o_slots  = 11725088;    // 3,200,000 (50000 * 64 ints)
    // ---- contiguous zero block from here ----
    const size_t o_deg    = 14925088;    // 50,000
    const size_t o_pool   = 14975088;    // 65,536
    const size_t o_bcnt   = 15040624;    // 256
    const size_t total    = 15040880;    // ~60 MB

    int* p_slots = (int*)(ws + o_slots);
    int* p_deg   = (int*)(ws + o_deg);
    int* p_bcnt  = (int*)(ws + o_bcnt);
    uint2* p_ebuf = (uint2*)(ws + o_xagg);          // aliases xagg (consumed before xagg write)
    unsigned short* p_xbf  = (unsigned short*)(ws + o_xbf);
    unsigned short* p_xagg = (unsigned short*)(ws + o_xagg);
    unsigned short* p_h2bf = (unsigned short*)(ws + o_h2bf);
    unsigned short* p_w1p  = (unsigned short*)(ws + o_w1p);
    unsigned short* p_w2p  = (unsigned short*)(ws + o_w2p);

    hipMemsetAsync(ws + o_deg, 0, (total - o_deg) * sizeof(float), stream);

    // ---- frontA: weights (fragment-linear) + att projections ----
    k_frontA<<<385, 256, 0, stream>>>(W1, W2, atts1, attd1,
                                      p_w1p, p_w2p, ws + o_wproj);
    // ---- mid: pass-1 bucket partition + layer-1 logits / x cast ----
    k_mid<<<NBUILD + NATT, 256, 0, stream>>>(src, dst, p_bcnt, p_ebuf,
                                             x, ws + o_wproj, p_xbf,
                                             ws + o_as1, ws + o_ad1);
    // ---- pass-2: per-bucket scatter (LDS degree counters) ----
    k_scat<<<NBUCK, 256, 0, stream>>>(p_bcnt, p_ebuf, p_deg, p_slots);

    const int nagg1 = N_NODES / 16;             // 3125: 4 waves x 4 nodes per block
    const int nagg2 = N_NODES / 8;              // 6250: 4 waves x 2 nodes per block
    const int nmfma = (N_NODES + 63) / 64;      // 782: 4 waves x 16 nodes per block

    // ---- layer 1 aggregate + fused GEMM chain ----
    k_l1_agg<<<nagg1, 256, 0, stream>>>(p_deg, p_slots, ws + o_as1, ws + o_ad1,
                                        (const uint2*)p_xbf, p_xagg);
    k_gemm12<<<nmfma, 256, 0, stream>>>(p_xagg, p_w1p, b1, p_w2p, atts2, attd2,
                                        p_h2bf, ws + o_as2, ws + o_ad2);

    // ---- layer 2 aggregate + pool ----
    k_l2_aggpool<<<nagg2, 256, 0, stream>>>(p_deg, p_slots, ws + o_as2, ws + o_ad2,
                                            p_h2bf, b2, batch, ws + o_pool);

    // ---- BN (cnt via binary search, no atomics) ----
    k_bn<<<C2, 512, 0, stream>>>(ws + o_pool, batch, gamma, beta, out);
}